// Round 1
// baseline (9034.470 us; speedup 1.0000x reference)
//
#include <hip/hip_runtime.h>
#include <hip/hip_bf16.h>

#define HID 64

// ---------------- init: gcn_deg=1 (self loop), odeg=0, infl=0, maxima=0 ----
__global__ void k_init(float* __restrict__ gdeg, float* __restrict__ odeg,
                       float* __restrict__ infl, unsigned* __restrict__ maxima, int n) {
    int i = blockIdx.x * blockDim.x + threadIdx.x;
    if (i < n) { gdeg[i] = 1.0f; odeg[i] = 0.0f; infl[i] = 0.0f; }
    if (i < 2) maxima[i] = 0u;
}

// ---------------- edge pass 1: degrees ------------------------------------
__global__ void k_edge_deg(const int* __restrict__ row, const int* __restrict__ col,
                           float* __restrict__ gdeg, float* __restrict__ odeg, int E) {
    int e = blockIdx.x * blockDim.x + threadIdx.x;
    if (e < E) {
        atomicAdd(&gdeg[col[e]], 1.0f);   // in-degree (+1 self loop from init)
        atomicAdd(&odeg[row[e]], 1.0f);   // structural out-degree
    }
}

// ---------------- edge pass 2: influence sum ------------------------------
__global__ void k_edge_infl(const int* __restrict__ row, const int* __restrict__ col,
                            const float* __restrict__ odeg, float* __restrict__ infl, int E) {
    int e = blockIdx.x * blockDim.x + threadIdx.x;
    if (e < E) atomicAdd(&infl[row[e]], odeg[col[e]]);
}

// ---------------- node stats: dis=rsqrt(deg), infl_raw, maxima ------------
__global__ void k_node_stats(const float* __restrict__ gdeg, const float* __restrict__ odeg,
                             float* __restrict__ infl, float* __restrict__ dis,
                             unsigned* __restrict__ maxima, int n) {
    int i = blockIdx.x * blockDim.x + threadIdx.x;
    float od = 0.0f, fin = 0.0f;
    if (i < n) {
        dis[i] = rsqrtf(gdeg[i]);             // gdeg >= 1 always
        od = odeg[i];
        float is = infl[i];
        fin = (od > 0.0f) ? is / fmaxf(od, 1.0f) : 0.0f;
        infl[i] = fin;
    }
    // wave(64) max-reduce, then one atomic per wave (values are >= 0 so uint order == float order)
    for (int off = 32; off > 0; off >>= 1) {
        od  = fmaxf(od,  __shfl_down(od,  off));
        fin = fmaxf(fin, __shfl_down(fin, off));
    }
    if ((threadIdx.x & 63) == 0) {
        atomicMax(&maxima[0], __float_as_uint(od));
        atomicMax(&maxima[1], __float_as_uint(fin));
    }
}

// ---------------- h0 = x @ W_in + b_in  ([N,128]x[128,64]) ----------------
__global__ __launch_bounds__(256) void k_in_proj(const float* __restrict__ x,
                                                 const float* __restrict__ W,
                                                 const float* __restrict__ b,
                                                 float* __restrict__ h, int n) {
    __shared__ float Ws[128 * 64];   // 32 KB
    __shared__ float xs[64 * 64];    // 16 KB (half of k at a time)
    int t = threadIdx.x;
    int r0 = blockIdx.x * 64;
    for (int i = t; i < 128 * 64; i += 256) Ws[i] = W[i];

    int c = t & 63, rg = t >> 6;     // rg in 0..3, 16 rows each
    float acc[16];
    float bc = b[c];
#pragma unroll
    for (int i = 0; i < 16; ++i) acc[i] = bc;

    for (int half = 0; half < 2; ++half) {
        __syncthreads();
        for (int i = t; i < 64 * 16; i += 256) {  // 64 rows x 16 float4
            int rr = i >> 4, k4 = i & 15;
            int r = r0 + rr;
            float4 v = (r < n) ? ((const float4*)x)[(size_t)r * 32 + half * 16 + k4]
                               : make_float4(0.f, 0.f, 0.f, 0.f);
            ((float4*)xs)[i] = v;
        }
        __syncthreads();
        for (int k = 0; k < 64; ++k) {
            float wv = Ws[(half * 64 + k) * 64 + c];
#pragma unroll
            for (int i = 0; i < 16; ++i)
                acc[i] = fmaf(xs[(rg * 16 + i) * 64 + k], wv, acc[i]);
        }
    }
#pragma unroll
    for (int i = 0; i < 16; ++i) {
        int r = r0 + rg * 16 + i;
        if (r < n) h[(size_t)r * 64 + c] = acc[i];
    }
}

// -------- hw = h @ W_gcn; hws = hw*dis[r]; acc = hw*dis[r]^2 (self loop) --
__global__ __launch_bounds__(256) void k_gcn_mm(const float* __restrict__ h,
                                                const float* __restrict__ Wg,
                                                const float* __restrict__ dis,
                                                float* __restrict__ hws,
                                                float* __restrict__ accb, int n) {
    __shared__ float Ws[64 * 64];    // 16 KB
    __shared__ float xs[64 * 64];    // 16 KB
    int t = threadIdx.x;
    int r0 = blockIdx.x * 64;
    for (int i = t; i < 64 * 64; i += 256) Ws[i] = Wg[i];
    for (int i = t; i < 64 * 16; i += 256) {
        int rr = i >> 4, k4 = i & 15;
        int r = r0 + rr;
        float4 v = (r < n) ? ((const float4*)h)[(size_t)r * 16 + k4]
                           : make_float4(0.f, 0.f, 0.f, 0.f);
        ((float4*)xs)[i] = v;
    }
    __syncthreads();
    int c = t & 63, rg = t >> 6;
    float acc[16];
#pragma unroll
    for (int i = 0; i < 16; ++i) acc[i] = 0.f;
    for (int k = 0; k < 64; ++k) {
        float wv = Ws[k * 64 + c];
#pragma unroll
        for (int i = 0; i < 16; ++i)
            acc[i] = fmaf(xs[(rg * 16 + i) * 64 + k], wv, acc[i]);
    }
#pragma unroll
    for (int i = 0; i < 16; ++i) {
        int r = r0 + rg * 16 + i;
        if (r < n) {
            float d = dis[r];
            float v = acc[i] * d;
            hws[(size_t)r * 64 + c] = v;
            accb[(size_t)r * 64 + c] = v * d;   // self-loop term hw*dis^2
        }
    }
}

// -------- scatter: acc[col] += hws[row] * dis[col]  (16 threads / edge) ---
__global__ __launch_bounds__(256) void k_scatter(const int* __restrict__ row,
                                                 const int* __restrict__ col,
                                                 const float* __restrict__ dis,
                                                 const float* __restrict__ hws,
                                                 float* __restrict__ acc, int total) {
    int idx0 = blockIdx.x * blockDim.x + threadIdx.x;
    int stride = gridDim.x * blockDim.x;
    for (int it = idx0; it < total; it += stride) {
        int e = it >> 4;
        int q = it & 15;
        int r = row[e], c = col[e];
        float w = dis[c];
        float4 v = ((const float4*)hws)[(size_t)r * 16 + q];
        float* dst = acc + (size_t)c * 64 + q * 4;
        atomicAdd(dst + 0, v.x * w);
        atomicAdd(dst + 1, v.y * w);
        atomicAdd(dst + 2, v.z * w);
        atomicAdd(dst + 3, v.w * w);
    }
}

// -------- epilogue: h = relu((acc + b_gcn) * gamma/sqrt(1+eps) + beta) ----
__global__ void k_epilogue(const float* __restrict__ acc, const float* __restrict__ bg,
                           const float* __restrict__ gamma, const float* __restrict__ beta,
                           float* __restrict__ h, int n) {
    int t = blockIdx.x * blockDim.x + threadIdx.x;   // n*16 threads (float4 each)
    if (t >= n * 16) return;
    int f4 = (t & 15) * 4;
    float4 a = ((const float4*)acc)[t];
    float inv = rsqrtf(1.0f + 1e-5f);
    float av[4] = {a.x, a.y, a.z, a.w};
    float ov[4];
#pragma unroll
    for (int j = 0; j < 4; ++j) {
        int f = f4 + j;
        float s = gamma[f] * inv;
        ov[j] = fmaxf(fmaf(av[j] + bg[f], s, beta[f]), 0.0f);
    }
    ((float4*)h)[t] = make_float4(ov[0], ov[1], ov[2], ov[3]);
}

// -------- fused structural MLP + output head (one node per thread) --------
__global__ __launch_bounds__(256) void k_final(const float* __restrict__ h,
                                               const float* __restrict__ odeg,
                                               const float* __restrict__ infl,
                                               const unsigned* __restrict__ maxima,
                                               const float* __restrict__ Ws1, const float* __restrict__ bs1,
                                               const float* __restrict__ Ws2, const float* __restrict__ bs2,
                                               const float* __restrict__ Wo1, const float* __restrict__ bo1,
                                               const float* __restrict__ Wo2, const float* __restrict__ bo2,
                                               const float* __restrict__ Wo3, const float* __restrict__ bo3,
                                               float* __restrict__ out, int n) {
    __shared__ float sWs1[96], sbs1[32], sWs2[32 * 64], sbs2[64];
    __shared__ float sWo1[128 * 64], sbo1[64], sWo2[64 * 32], sbo2[32], sWo3[32];
    int t = threadIdx.x;
    for (int i = t; i < 96; i += 256) sWs1[i] = Ws1[i];
    for (int i = t; i < 2048; i += 256) sWs2[i] = Ws2[i];
    for (int i = t; i < 8192; i += 256) sWo1[i] = Wo1[i];
    for (int i = t; i < 2048; i += 256) sWo2[i] = Wo2[i];
    if (t < 32) { sbs1[t] = bs1[t]; sbo2[t] = bo2[t]; sWo3[t] = Wo3[t]; }
    if (t < 64) { sbs2[t] = bs2[t]; sbo1[t] = bo1[t]; }
    __syncthreads();

    int i = blockIdx.x * 256 + t;
    if (i >= n) return;

    float dmax = __uint_as_float(maxima[0]);
    float imax = __uint_as_float(maxima[1]);
    float od = odeg[i];
    float sf0 = (dmax > 0.0f) ? od / dmax : od;
    float fin = infl[i];
    float sf2 = (imax > 0.0f) ? fin / imax : fin;
    // sf1 (clustering) is identically 0

    // hid = relu(sf @ W_s1 + b_s1); W_s1 is [3][32]
    float hid[32];
#pragma unroll
    for (int j = 0; j < 32; ++j)
        hid[j] = fmaxf(fmaf(sf0, sWs1[j], fmaf(sf2, sWs1[64 + j], sbs1[j])), 0.0f);

    // o1 = concat(h, se) @ W_o1 + b_o1
    float o1[64];
#pragma unroll
    for (int c = 0; c < 64; ++c) o1[c] = sbo1[c];

    // h part
    const float4* hrow = (const float4*)(h + (size_t)i * 64);
    for (int k4 = 0; k4 < 16; ++k4) {
        float4 hv = hrow[k4];
        float hv_[4] = {hv.x, hv.y, hv.z, hv.w};
#pragma unroll
        for (int j = 0; j < 4; ++j) {
            float hk = hv_[j];
            int k = k4 * 4 + j;
#pragma unroll
            for (int c = 0; c < 64; ++c)
                o1[c] = fmaf(hk, sWo1[k * 64 + c], o1[c]);
        }
    }
    // se part: se[k] = hid @ W_s2[:,k] + b_s2[k]
    for (int k = 0; k < 64; ++k) {
        float sek = sbs2[k];
#pragma unroll
        for (int j = 0; j < 32; ++j) sek = fmaf(hid[j], sWs2[j * 64 + k], sek);
#pragma unroll
        for (int c = 0; c < 64; ++c)
            o1[c] = fmaf(sek, sWo1[(64 + k) * 64 + c], o1[c]);
    }

    // o2 = relu(o1) @ W_o2 + b_o2
    float o2[32];
#pragma unroll
    for (int c2 = 0; c2 < 32; ++c2) o2[c2] = sbo2[c2];
#pragma unroll
    for (int c = 0; c < 64; ++c) {
        float v = fmaxf(o1[c], 0.0f);
#pragma unroll
        for (int c2 = 0; c2 < 32; ++c2)
            o2[c2] = fmaf(v, sWo2[c * 32 + c2], o2[c2]);
    }

    float o3 = bo3[0];
#pragma unroll
    for (int c2 = 0; c2 < 32; ++c2)
        o3 = fmaf(fmaxf(o2[c2], 0.0f), sWo3[c2], o3);

    out[i] = 1.0f / (1.0f + __expf(-o3));
}

// ==========================================================================
extern "C" void kernel_launch(void* const* d_in, const int* in_sizes, int n_in,
                              void* d_out, int out_size, void* d_ws, size_t ws_size,
                              hipStream_t stream) {
    const float* x     = (const float*)d_in[0];
    const int*   ei    = (const int*)d_in[1];
    const float* W_in  = (const float*)d_in[2];
    const float* b_in  = (const float*)d_in[3];
    const float* W_gcn = (const float*)d_in[4];
    const float* b_gcn = (const float*)d_in[5];
    const float* gamma = (const float*)d_in[6];
    const float* beta  = (const float*)d_in[7];
    const float* Ws1   = (const float*)d_in[8];
    const float* bs1   = (const float*)d_in[9];
    const float* Ws2   = (const float*)d_in[10];
    const float* bs2   = (const float*)d_in[11];
    const float* Wo1   = (const float*)d_in[12];
    const float* bo1   = (const float*)d_in[13];
    const float* Wo2   = (const float*)d_in[14];
    const float* bo2   = (const float*)d_in[15];
    const float* Wo3   = (const float*)d_in[16];
    const float* bo3   = (const float*)d_in[17];
    float* out = (float*)d_out;

    int n = in_sizes[0] / 128;
    int E = in_sizes[1] / 2;
    const int* row = ei;
    const int* col = ei + E;

    // workspace layout (floats)
    float* ws = (float*)d_ws;
    int NP = (n + 511) & ~511;
    float* dis   = ws;
    float* odeg  = ws + (size_t)NP;
    float* infl  = ws + (size_t)2 * NP;
    unsigned* maxima = (unsigned*)(ws + (size_t)3 * NP);
    float* h    = ws + (size_t)3 * NP + 128;
    float* hws  = h   + (size_t)NP * 64;
    float* acc  = hws + (size_t)NP * 64;

    int nb_n = (n + 255) / 256;
    int nb_e = (E + 255) / 256;

    k_init<<<nb_n, 256, 0, stream>>>(dis /*gdeg reuse*/, odeg, infl, maxima, n);
    // NOTE: gdeg lives in `dis` buffer temporarily; k_node_stats converts in-place.
    k_edge_deg<<<nb_e, 256, 0, stream>>>(row, col, dis, odeg, E);
    k_edge_infl<<<nb_e, 256, 0, stream>>>(row, col, odeg, infl, E);
    k_node_stats<<<nb_n, 256, 0, stream>>>(dis, odeg, infl, dis, maxima, n);

    k_in_proj<<<(n + 63) / 64, 256, 0, stream>>>(x, W_in, b_in, h, n);

    int total = E * 16;
    for (int l = 0; l < 3; ++l) {
        k_gcn_mm<<<(n + 63) / 64, 256, 0, stream>>>(h, W_gcn + (size_t)l * 64 * 64, dis, hws, acc, n);
        k_scatter<<<4096, 256, 0, stream>>>(row, col, dis, hws, acc, total);
        k_epilogue<<<(n * 16 + 255) / 256, 256, 0, stream>>>(acc, b_gcn + l * 64, gamma + l * 64,
                                                             beta + l * 64, h, n);
    }

    k_final<<<nb_n, 256, 0, stream>>>(h, odeg, infl, maxima,
                                      Ws1, bs1, Ws2, bs2, Wo1, bo1, Wo2, bo2, Wo3, bo3,
                                      out, n);
}

// Round 2
// 1461.254 us; speedup vs baseline: 6.1827x; 6.1827x over previous
//
#include <hip/hip_runtime.h>
#include <hip/hip_bf16.h>

#define HID 64

// ---------------- init: cnt=0, odeg=0, infl=0, maxima=0 -------------------
__global__ void k_init(int* __restrict__ cnt, float* __restrict__ odeg,
                       float* __restrict__ infl, unsigned* __restrict__ maxima, int n) {
    int i = blockIdx.x * blockDim.x + threadIdx.x;
    if (i < n) { cnt[i] = 0; odeg[i] = 0.0f; infl[i] = 0.0f; }
    if (i < 2) maxima[i] = 0u;
}

// ---------------- edge pass 1: in-degree count (int) + out-degree ---------
__global__ void k_edge_deg(const int* __restrict__ row, const int* __restrict__ col,
                           int* __restrict__ cnt, float* __restrict__ odeg, int E) {
    int e = blockIdx.x * blockDim.x + threadIdx.x;
    if (e < E) {
        atomicAdd(&cnt[col[e]], 1);
        atomicAdd(&odeg[row[e]], 1.0f);
    }
}

// ---------------- edge pass 2: influence sum ------------------------------
__global__ void k_edge_infl(const int* __restrict__ row, const int* __restrict__ col,
                            const float* __restrict__ odeg, float* __restrict__ infl, int E) {
    int e = blockIdx.x * blockDim.x + threadIdx.x;
    if (e < E) atomicAdd(&infl[row[e]], odeg[col[e]]);
}

// ---------------- scan stage 1: per-256-block exclusive scan of cnt -------
__global__ __launch_bounds__(256) void k_scan1(const int* __restrict__ cnt,
                                               int* __restrict__ roff,
                                               int* __restrict__ bsum, int n) {
    __shared__ int s[256];
    int b = blockIdx.x, t = threadIdx.x;
    int i = b * 256 + t;
    int v = (i < n) ? cnt[i] : 0;
    s[t] = v;
    __syncthreads();
    for (int off = 1; off < 256; off <<= 1) {
        int x = (t >= off) ? s[t - off] : 0;
        __syncthreads();
        s[t] += x;
        __syncthreads();
    }
    if (i < n) roff[i] = s[t] - v;       // block-local exclusive
    if (t == 255) bsum[b] = s[255];      // block total
}

// ---------------- scan stage 2: exclusive scan of block sums (1 block) ----
__global__ __launch_bounds__(512) void k_scan2(int* __restrict__ bsum, int nb) {
    __shared__ int s[512];
    int t = threadIdx.x;
    int v = (t < nb) ? bsum[t] : 0;
    s[t] = v;
    __syncthreads();
    for (int off = 1; off < 512; off <<= 1) {
        int x = (t >= off) ? s[t - off] : 0;
        __syncthreads();
        s[t] += x;
        __syncthreads();
    }
    if (t < nb) bsum[t] = s[t] - v;
}

// ---- scan stage 3: finalize roff/cursor + node stats (dis, infl, maxima) -
__global__ void k_scan3(int* __restrict__ roff, const int* __restrict__ bsum,
                        int* __restrict__ cursor, const int* __restrict__ cnt,
                        const float* __restrict__ odeg, float* __restrict__ infl,
                        float* __restrict__ dis, unsigned* __restrict__ maxima,
                        int n, int E) {
    int i = blockIdx.x * blockDim.x + threadIdx.x;
    float od = 0.0f, fin = 0.0f;
    if (i < n) {
        int r = roff[i] + bsum[i >> 8];
        roff[i] = r;
        cursor[i] = r;
        dis[i] = rsqrtf((float)cnt[i] + 1.0f);   // +1 self loop, deg >= 1
        od = odeg[i];
        float is = infl[i];
        fin = (od > 0.0f) ? is / fmaxf(od, 1.0f) : 0.0f;
        infl[i] = fin;
    }
    if (i == 0) roff[n] = E;
    for (int off = 32; off > 0; off >>= 1) {
        od  = fmaxf(od,  __shfl_down(od,  off));
        fin = fmaxf(fin, __shfl_down(fin, off));
    }
    if ((threadIdx.x & 63) == 0) {
        atomicMax(&maxima[0], __float_as_uint(od));
        atomicMax(&maxima[1], __float_as_uint(fin));
    }
}

// ---------------- CSR fill: esrc[pos] = row, bucketed by col --------------
__global__ void k_fill(const int* __restrict__ row, const int* __restrict__ col,
                       int* __restrict__ cursor, int* __restrict__ esrc, int E) {
    int e = blockIdx.x * blockDim.x + threadIdx.x;
    if (e < E) {
        int pos = atomicAdd(&cursor[col[e]], 1);
        esrc[pos] = row[e];
    }
}

// ---------------- h0 = x @ W_in + b_in  ([N,128]x[128,64]) ----------------
__global__ __launch_bounds__(256) void k_in_proj(const float* __restrict__ x,
                                                 const float* __restrict__ W,
                                                 const float* __restrict__ b,
                                                 float* __restrict__ h, int n) {
    __shared__ float Ws[128 * 64];   // 32 KB
    __shared__ float xs[64 * 64];    // 16 KB (half of k at a time)
    int t = threadIdx.x;
    int r0 = blockIdx.x * 64;
    for (int i = t; i < 128 * 64; i += 256) Ws[i] = W[i];

    int c = t & 63, rg = t >> 6;     // rg in 0..3, 16 rows each
    float acc[16];
    float bc = b[c];
#pragma unroll
    for (int i = 0; i < 16; ++i) acc[i] = bc;

    for (int half = 0; half < 2; ++half) {
        __syncthreads();
        for (int i = t; i < 64 * 16; i += 256) {
            int rr = i >> 4, k4 = i & 15;
            int r = r0 + rr;
            float4 v = (r < n) ? ((const float4*)x)[(size_t)r * 32 + half * 16 + k4]
                               : make_float4(0.f, 0.f, 0.f, 0.f);
            ((float4*)xs)[i] = v;
        }
        __syncthreads();
        for (int k = 0; k < 64; ++k) {
            float wv = Ws[(half * 64 + k) * 64 + c];
#pragma unroll
            for (int i = 0; i < 16; ++i)
                acc[i] = fmaf(xs[(rg * 16 + i) * 64 + k], wv, acc[i]);
        }
    }
#pragma unroll
    for (int i = 0; i < 16; ++i) {
        int r = r0 + rg * 16 + i;
        if (r < n) h[(size_t)r * 64 + c] = acc[i];
    }
}

// -------- hw = h @ W_gcn; hws = hw * dis[r]  ------------------------------
__global__ __launch_bounds__(256) void k_gcn_mm(const float* __restrict__ h,
                                                const float* __restrict__ Wg,
                                                const float* __restrict__ dis,
                                                float* __restrict__ hws, int n) {
    __shared__ float Ws[64 * 64];    // 16 KB
    __shared__ float xs[64 * 64];    // 16 KB
    int t = threadIdx.x;
    int r0 = blockIdx.x * 64;
    for (int i = t; i < 64 * 64; i += 256) Ws[i] = Wg[i];
    for (int i = t; i < 64 * 16; i += 256) {
        int rr = i >> 4, k4 = i & 15;
        int r = r0 + rr;
        float4 v = (r < n) ? ((const float4*)h)[(size_t)r * 16 + k4]
                           : make_float4(0.f, 0.f, 0.f, 0.f);
        ((float4*)xs)[i] = v;
    }
    __syncthreads();
    int c = t & 63, rg = t >> 6;
    float acc[16];
#pragma unroll
    for (int i = 0; i < 16; ++i) acc[i] = 0.f;
    for (int k = 0; k < 64; ++k) {
        float wv = Ws[k * 64 + c];
#pragma unroll
        for (int i = 0; i < 16; ++i)
            acc[i] = fmaf(xs[(rg * 16 + i) * 64 + k], wv, acc[i]);
    }
#pragma unroll
    for (int i = 0; i < 16; ++i) {
        int r = r0 + rg * 16 + i;
        if (r < n) hws[(size_t)r * 64 + c] = acc[i] * dis[r];
    }
}

// -------- gather + BN/bias/ReLU epilogue: one wave per node ---------------
__global__ __launch_bounds__(256) void k_gather(const int* __restrict__ roff,
                                                const int* __restrict__ esrc,
                                                const float* __restrict__ hws,
                                                const float* __restrict__ dis,
                                                const float* __restrict__ bg,
                                                const float* __restrict__ gamma,
                                                const float* __restrict__ beta,
                                                float* __restrict__ h, int n) {
    int lane = threadIdx.x & 63;
    int node = blockIdx.x * 4 + (threadIdx.x >> 6);
    if (node >= n) return;
    int beg = roff[node], end = roff[node + 1];
    float acc = hws[(size_t)node * 64 + lane];   // self-loop term (hw*dis)
    int e = beg;
    for (; e + 4 <= end; e += 4) {
        int r0 = esrc[e], r1 = esrc[e + 1], r2 = esrc[e + 2], r3 = esrc[e + 3];
        float a0 = hws[(size_t)r0 * 64 + lane];
        float a1 = hws[(size_t)r1 * 64 + lane];
        float a2 = hws[(size_t)r2 * 64 + lane];
        float a3 = hws[(size_t)r3 * 64 + lane];
        acc += (a0 + a1) + (a2 + a3);
    }
    for (; e < end; ++e) acc += hws[(size_t)esrc[e] * 64 + lane];
    acc *= dis[node];                            // outer dis[col]
    float s = gamma[lane] * rsqrtf(1.0f + 1e-5f);
    h[(size_t)node * 64 + lane] = fmaxf(fmaf(acc + bg[lane], s, beta[lane]), 0.0f);
}

// -------- fused structural MLP + output head (one node per thread) --------
__global__ __launch_bounds__(256) void k_final(const float* __restrict__ h,
                                               const float* __restrict__ odeg,
                                               const float* __restrict__ infl,
                                               const unsigned* __restrict__ maxima,
                                               const float* __restrict__ Ws1, const float* __restrict__ bs1,
                                               const float* __restrict__ Ws2, const float* __restrict__ bs2,
                                               const float* __restrict__ Wo1, const float* __restrict__ bo1,
                                               const float* __restrict__ Wo2, const float* __restrict__ bo2,
                                               const float* __restrict__ Wo3, const float* __restrict__ bo3,
                                               float* __restrict__ out, int n) {
    __shared__ float sWs1[96], sbs1[32], sWs2[32 * 64], sbs2[64];
    __shared__ float sWo1[128 * 64], sbo1[64], sWo2[64 * 32], sbo2[32], sWo3[32];
    int t = threadIdx.x;
    for (int i = t; i < 96; i += 256) sWs1[i] = Ws1[i];
    for (int i = t; i < 2048; i += 256) sWs2[i] = Ws2[i];
    for (int i = t; i < 8192; i += 256) sWo1[i] = Wo1[i];
    for (int i = t; i < 2048; i += 256) sWo2[i] = Wo2[i];
    if (t < 32) { sbs1[t] = bs1[t]; sbo2[t] = bo2[t]; sWo3[t] = Wo3[t]; }
    if (t < 64) { sbs2[t] = bs2[t]; sbo1[t] = bo1[t]; }
    __syncthreads();

    int i = blockIdx.x * 256 + t;
    if (i >= n) return;

    float dmax = __uint_as_float(maxima[0]);
    float imax = __uint_as_float(maxima[1]);
    float od = odeg[i];
    float sf0 = (dmax > 0.0f) ? od / dmax : od;
    float fin = infl[i];
    float sf2 = (imax > 0.0f) ? fin / imax : fin;

    float hid[32];
#pragma unroll
    for (int j = 0; j < 32; ++j)
        hid[j] = fmaxf(fmaf(sf0, sWs1[j], fmaf(sf2, sWs1[64 + j], sbs1[j])), 0.0f);

    float o1[64];
#pragma unroll
    for (int c = 0; c < 64; ++c) o1[c] = sbo1[c];

    const float4* hrow = (const float4*)(h + (size_t)i * 64);
    for (int k4 = 0; k4 < 16; ++k4) {
        float4 hv = hrow[k4];
        float hv_[4] = {hv.x, hv.y, hv.z, hv.w};
#pragma unroll
        for (int j = 0; j < 4; ++j) {
            float hk = hv_[j];
            int k = k4 * 4 + j;
#pragma unroll
            for (int c = 0; c < 64; ++c)
                o1[c] = fmaf(hk, sWo1[k * 64 + c], o1[c]);
        }
    }
    for (int k = 0; k < 64; ++k) {
        float sek = sbs2[k];
#pragma unroll
        for (int j = 0; j < 32; ++j) sek = fmaf(hid[j], sWs2[j * 64 + k], sek);
#pragma unroll
        for (int c = 0; c < 64; ++c)
            o1[c] = fmaf(sek, sWo1[(64 + k) * 64 + c], o1[c]);
    }

    float o2[32];
#pragma unroll
    for (int c2 = 0; c2 < 32; ++c2) o2[c2] = sbo2[c2];
#pragma unroll
    for (int c = 0; c < 64; ++c) {
        float v = fmaxf(o1[c], 0.0f);
#pragma unroll
        for (int c2 = 0; c2 < 32; ++c2)
            o2[c2] = fmaf(v, sWo2[c * 32 + c2], o2[c2]);
    }

    float o3 = bo3[0];
#pragma unroll
    for (int c2 = 0; c2 < 32; ++c2)
        o3 = fmaf(fmaxf(o2[c2], 0.0f), sWo3[c2], o3);

    out[i] = 1.0f / (1.0f + __expf(-o3));
}

// ==========================================================================
extern "C" void kernel_launch(void* const* d_in, const int* in_sizes, int n_in,
                              void* d_out, int out_size, void* d_ws, size_t ws_size,
                              hipStream_t stream) {
    const float* x     = (const float*)d_in[0];
    const int*   ei    = (const int*)d_in[1];
    const float* W_in  = (const float*)d_in[2];
    const float* b_in  = (const float*)d_in[3];
    const float* W_gcn = (const float*)d_in[4];
    const float* b_gcn = (const float*)d_in[5];
    const float* gamma = (const float*)d_in[6];
    const float* beta  = (const float*)d_in[7];
    const float* Ws1   = (const float*)d_in[8];
    const float* bs1   = (const float*)d_in[9];
    const float* Ws2   = (const float*)d_in[10];
    const float* bs2   = (const float*)d_in[11];
    const float* Wo1   = (const float*)d_in[12];
    const float* bo1   = (const float*)d_in[13];
    const float* Wo2   = (const float*)d_in[14];
    const float* bo2   = (const float*)d_in[15];
    const float* Wo3   = (const float*)d_in[16];
    const float* bo3   = (const float*)d_in[17];
    float* out = (float*)d_out;

    int n = in_sizes[0] / 128;
    int E = in_sizes[1] / 2;
    const int* row = ei;
    const int* col = ei + E;

    // workspace layout
    float* ws = (float*)d_ws;
    int NP = (n + 511) & ~511;
    float* dis   = ws;
    float* odeg  = ws + (size_t)NP;
    float* infl  = ws + (size_t)2 * NP;
    unsigned* maxima = (unsigned*)(ws + (size_t)3 * NP);
    int* cnt    = (int*)(ws + (size_t)3 * NP + 128);
    int* roff   = cnt + NP;            // n+1 entries
    int* cursor = roff + NP + 128;
    int* bsum   = cursor + NP;         // up to 1024 block sums
    int* esrc   = bsum + 1024;         // E entries
    float* h    = (float*)(esrc + ((E + 511) & ~511));
    float* hws  = h + (size_t)NP * 64;

    int nb_n = (n + 255) / 256;
    int nb_e = (E + 255) / 256;
    int nblk = nb_n;                   // scan1 blocks (256 elems each)

    k_init<<<nb_n, 256, 0, stream>>>(cnt, odeg, infl, maxima, n);
    k_edge_deg<<<nb_e, 256, 0, stream>>>(row, col, cnt, odeg, E);
    k_edge_infl<<<nb_e, 256, 0, stream>>>(row, col, odeg, infl, E);
    k_scan1<<<nblk, 256, 0, stream>>>(cnt, roff, bsum, n);
    k_scan2<<<1, 512, 0, stream>>>(bsum, nblk);
    k_scan3<<<nb_n, 256, 0, stream>>>(roff, bsum, cursor, cnt, odeg, infl, dis, maxima, n, E);
    k_fill<<<nb_e, 256, 0, stream>>>(row, col, cursor, esrc, E);

    k_in_proj<<<(n + 63) / 64, 256, 0, stream>>>(x, W_in, b_in, h, n);

    for (int l = 0; l < 3; ++l) {
        k_gcn_mm<<<(n + 63) / 64, 256, 0, stream>>>(h, W_gcn + (size_t)l * 64 * 64, dis, hws, n);
        k_gather<<<(n + 3) / 4, 256, 0, stream>>>(roff, esrc, hws, dis,
                                                  b_gcn + l * 64, gamma + l * 64, beta + l * 64,
                                                  h, n);
    }

    k_final<<<nb_n, 256, 0, stream>>>(h, odeg, infl, maxima,
                                      Ws1, bs1, Ws2, bs2, Wo1, bo1, Wo2, bo2, Wo3, bo3,
                                      out, n);
}

// Round 3
// 1450.492 us; speedup vs baseline: 6.2286x; 1.0074x over previous
//
#include <hip/hip_runtime.h>
#include <hip/hip_bf16.h>

#define NBINS 16384
#define TPBH 512

// ---------------- init: maxima=0 ------------------------------------------
__global__ void k_init(unsigned* __restrict__ maxima) {
    if (threadIdx.x < 2) maxima[threadIdx.x] = 0u;
}

// ---- LDS histogram over keys -> u16 per-block partials (block-major) -----
__global__ __launch_bounds__(TPBH) void kh_hist(const int* __restrict__ keys,
                                                unsigned short* __restrict__ part,
                                                int E, int chunk, int npu, int npass) {
    __shared__ unsigned bins[NBINS];          // 64 KB
    int b = blockIdx.x, t = threadIdx.x;
    int e0 = b * chunk, e1 = min(E, e0 + chunk);
    for (int p = 0; p < npass; ++p) {
        int base = p * NBINS;
        for (int j = t; j < NBINS; j += TPBH) bins[j] = 0u;
        __syncthreads();
        for (int e = e0 + t; e < e1; e += TPBH) {
            int k = keys[e] - base;
            if ((unsigned)k < NBINS) atomicAdd(&bins[k], 1u);
        }
        __syncthreads();
        unsigned* dst = (unsigned*)(part + (size_t)b * npu + base);
        for (int j = t; j < NBINS / 2; j += TPBH)
            dst[j] = (bins[2 * j] & 0xFFFFu) | (bins[2 * j + 1] << 16);
        __syncthreads();
    }
}

// ---- reduce u16 partials -> int counts -----------------------------------
__global__ void kh_reduce_cnt(const unsigned short* __restrict__ part, int* __restrict__ cnt,
                              int nb, int npu, int n) {
    int i = blockIdx.x * blockDim.x + threadIdx.x;
    if (i >= n) return;
    int s = 0;
    for (int b = 0; b < nb; ++b) s += part[(size_t)b * npu + i];
    cnt[i] = s;
}

// ---- reduce u16 partials -> float odeg + dmax ----------------------------
__global__ void kh_reduce_odeg(const unsigned short* __restrict__ part, float* __restrict__ odeg,
                               unsigned* __restrict__ maxima, int nb, int npu, int n) {
    int i = blockIdx.x * blockDim.x + threadIdx.x;
    float od = 0.f;
    if (i < n) {
        int s = 0;
        for (int b = 0; b < nb; ++b) s += part[(size_t)b * npu + i];
        od = (float)s;
        odeg[i] = od;
    }
    for (int off = 32; off > 0; off >>= 1) od = fmaxf(od, __shfl_down(od, off));
    if ((threadIdx.x & 63) == 0) atomicMax(&maxima[0], __float_as_uint(od));
}

// ---- scan stage 1: per-256-block exclusive scan of cnt -> roff-local -----
__global__ __launch_bounds__(256) void k_scan1(const int* __restrict__ cnt,
                                               int* __restrict__ roff,
                                               int* __restrict__ bsum, int n) {
    __shared__ int s[256];
    int b = blockIdx.x, t = threadIdx.x;
    int i = b * 256 + t;
    int v = (i < n) ? cnt[i] : 0;
    s[t] = v;
    __syncthreads();
    for (int off = 1; off < 256; off <<= 1) {
        int x = (t >= off) ? s[t - off] : 0;
        __syncthreads();
        s[t] += x;
        __syncthreads();
    }
    if (i < n) roff[i] = s[t] - v;
    if (t == 255) bsum[b] = s[255];
}

// ---- scan stage 2: exclusive scan of block sums (1 block) ----------------
__global__ __launch_bounds__(512) void k_scan2(int* __restrict__ bsum, int nb) {
    __shared__ int s[512];
    int t = threadIdx.x;
    int v = (t < nb) ? bsum[t] : 0;
    s[t] = v;
    __syncthreads();
    for (int off = 1; off < 512; off <<= 1) {
        int x = (t >= off) ? s[t - off] : 0;
        __syncthreads();
        s[t] += x;
        __syncthreads();
    }
    if (t < nb) bsum[t] = s[t] - v;
}

// ---- scan stage 3: finalize roff + dis -----------------------------------
__global__ void k_scan3(int* __restrict__ roff, const int* __restrict__ bsum,
                        const int* __restrict__ cnt, float* __restrict__ dis, int n, int E) {
    int i = blockIdx.x * blockDim.x + threadIdx.x;
    if (i < n) {
        roff[i] += bsum[i >> 8];
        dis[i] = rsqrtf((float)cnt[i] + 1.0f);    // +1 self loop
    }
    if (i == 0) roff[n] = E;
}

// ---- in-place per-node exclusive prefix of partials across blocks --------
__global__ void kh_prefix(unsigned short* __restrict__ part, int nb, int npu, int n) {
    int i = blockIdx.x * blockDim.x + threadIdx.x;
    if (i >= n) return;
    int run = 0;
    for (int b = 0; b < nb; ++b) {
        size_t idx = (size_t)b * npu + i;
        int v = part[idx];
        part[idx] = (unsigned short)run;
        run += v;
    }
}

// ---- CSR fill via LDS cursors (no global atomics) ------------------------
__global__ __launch_bounds__(TPBH) void kh_fill(const int* __restrict__ col,
                                                const int* __restrict__ row,
                                                const int* __restrict__ roff,
                                                const unsigned short* __restrict__ pref,
                                                int* __restrict__ esrc,
                                                int E, int chunk, int npu, int npass) {
    __shared__ unsigned curs[NBINS];          // 64 KB
    int b = blockIdx.x, t = threadIdx.x;
    int e0 = b * chunk, e1 = min(E, e0 + chunk);
    for (int p = 0; p < npass; ++p) {
        int base = p * NBINS;
        const unsigned short* pb = pref + (size_t)b * npu + base;
        const int* rb = roff + base;
        for (int j = t; j < NBINS; j += TPBH) curs[j] = (unsigned)rb[j] + pb[j];
        __syncthreads();
        for (int e = e0 + t; e < e1; e += TPBH) {
            int c = col[e] - base;
            if ((unsigned)c < NBINS) {
                unsigned slot = atomicAdd(&curs[c], 1u);
                esrc[slot] = row[e];
            }
        }
        __syncthreads();
    }
}

// ---- float LDS histogram-accumulate: part[row] += odeg[col] --------------
__global__ __launch_bounds__(TPBH) void kh_histacc(const int* __restrict__ row,
                                                   const int* __restrict__ col,
                                                   const float* __restrict__ odeg,
                                                   float* __restrict__ partf,
                                                   int E, int chunk, int npu, int npass) {
    __shared__ float binsf[NBINS];            // 64 KB
    int b = blockIdx.x, t = threadIdx.x;
    int e0 = b * chunk, e1 = min(E, e0 + chunk);
    for (int p = 0; p < npass; ++p) {
        int base = p * NBINS;
        for (int j = t; j < NBINS; j += TPBH) binsf[j] = 0.f;
        __syncthreads();
        for (int e = e0 + t; e < e1; e += TPBH) {
            int r = row[e] - base;
            if ((unsigned)r < NBINS) atomicAdd(&binsf[r], odeg[col[e]]);
        }
        __syncthreads();
        float* dst = partf + (size_t)b * npu + base;
        for (int j = t; j < NBINS; j += TPBH) dst[j] = binsf[j];
        __syncthreads();
    }
}

// ---- reduce float partials -> infl + imax --------------------------------
__global__ void kh_reduce_infl(const float* __restrict__ partf, const float* __restrict__ odeg,
                               float* __restrict__ infl, unsigned* __restrict__ maxima,
                               int nb, int npu, int n) {
    int i = blockIdx.x * blockDim.x + threadIdx.x;
    float fin = 0.f;
    if (i < n) {
        float s = 0.f;
        for (int b = 0; b < nb; ++b) s += partf[(size_t)b * npu + i];
        float od = odeg[i];
        fin = (od > 0.f) ? s / od : 0.f;
        infl[i] = fin;
    }
    for (int off = 32; off > 0; off >>= 1) fin = fmaxf(fin, __shfl_down(fin, off));
    if ((threadIdx.x & 63) == 0) atomicMax(&maxima[1], __float_as_uint(fin));
}

// ---------------- h0 = x @ W_in + b_in  ([N,128]x[128,64]) ----------------
__global__ __launch_bounds__(256) void k_in_proj(const float* __restrict__ x,
                                                 const float* __restrict__ W,
                                                 const float* __restrict__ b,
                                                 float* __restrict__ h, int n) {
    __shared__ float Ws[128 * 64];
    __shared__ float xs[64 * 64];
    int t = threadIdx.x;
    int r0 = blockIdx.x * 64;
    for (int i = t; i < 128 * 64; i += 256) Ws[i] = W[i];

    int c = t & 63, rg = t >> 6;
    float acc[16];
    float bc = b[c];
#pragma unroll
    for (int i = 0; i < 16; ++i) acc[i] = bc;

    for (int half = 0; half < 2; ++half) {
        __syncthreads();
        for (int i = t; i < 64 * 16; i += 256) {
            int rr = i >> 4, k4 = i & 15;
            int r = r0 + rr;
            float4 v = (r < n) ? ((const float4*)x)[(size_t)r * 32 + half * 16 + k4]
                               : make_float4(0.f, 0.f, 0.f, 0.f);
            ((float4*)xs)[i] = v;
        }
        __syncthreads();
        for (int k = 0; k < 64; ++k) {
            float wv = Ws[(half * 64 + k) * 64 + c];
#pragma unroll
            for (int i = 0; i < 16; ++i)
                acc[i] = fmaf(xs[(rg * 16 + i) * 64 + k], wv, acc[i]);
        }
    }
#pragma unroll
    for (int i = 0; i < 16; ++i) {
        int r = r0 + rg * 16 + i;
        if (r < n) h[(size_t)r * 64 + c] = acc[i];
    }
}

// -------- hw = h @ W_gcn; hws = hw * dis[r]  ------------------------------
__global__ __launch_bounds__(256) void k_gcn_mm(const float* __restrict__ h,
                                                const float* __restrict__ Wg,
                                                const float* __restrict__ dis,
                                                float* __restrict__ hws, int n) {
    __shared__ float Ws[64 * 64];
    __shared__ float xs[64 * 64];
    int t = threadIdx.x;
    int r0 = blockIdx.x * 64;
    for (int i = t; i < 64 * 64; i += 256) Ws[i] = Wg[i];
    for (int i = t; i < 64 * 16; i += 256) {
        int rr = i >> 4, k4 = i & 15;
        int r = r0 + rr;
        float4 v = (r < n) ? ((const float4*)h)[(size_t)r * 16 + k4]
                           : make_float4(0.f, 0.f, 0.f, 0.f);
        ((float4*)xs)[i] = v;
    }
    __syncthreads();
    int c = t & 63, rg = t >> 6;
    float acc[16];
#pragma unroll
    for (int i = 0; i < 16; ++i) acc[i] = 0.f;
    for (int k = 0; k < 64; ++k) {
        float wv = Ws[k * 64 + c];
#pragma unroll
        for (int i = 0; i < 16; ++i)
            acc[i] = fmaf(xs[(rg * 16 + i) * 64 + k], wv, acc[i]);
    }
#pragma unroll
    for (int i = 0; i < 16; ++i) {
        int r = r0 + rg * 16 + i;
        if (r < n) hws[(size_t)r * 64 + c] = acc[i] * dis[r];
    }
}

// -------- gather + BN/bias/ReLU epilogue: one wave per node ---------------
__global__ __launch_bounds__(256) void k_gather(const int* __restrict__ roff,
                                                const int* __restrict__ esrc,
                                                const float* __restrict__ hws,
                                                const float* __restrict__ dis,
                                                const float* __restrict__ bg,
                                                const float* __restrict__ gamma,
                                                const float* __restrict__ beta,
                                                float* __restrict__ h, int n) {
    int lane = threadIdx.x & 63;
    int node = blockIdx.x * 4 + (threadIdx.x >> 6);
    if (node >= n) return;
    int beg = roff[node], end = roff[node + 1];
    float acc = hws[(size_t)node * 64 + lane];   // self-loop term (hw*dis)
    int e = beg;
    for (; e + 4 <= end; e += 4) {
        int r0 = esrc[e], r1 = esrc[e + 1], r2 = esrc[e + 2], r3 = esrc[e + 3];
        float a0 = hws[(size_t)r0 * 64 + lane];
        float a1 = hws[(size_t)r1 * 64 + lane];
        float a2 = hws[(size_t)r2 * 64 + lane];
        float a3 = hws[(size_t)r3 * 64 + lane];
        acc += (a0 + a1) + (a2 + a3);
    }
    for (; e < end; ++e) acc += hws[(size_t)esrc[e] * 64 + lane];
    acc *= dis[node];
    float s = gamma[lane] * rsqrtf(1.0f + 1e-5f);
    h[(size_t)node * 64 + lane] = fmaxf(fmaf(acc + bg[lane], s, beta[lane]), 0.0f);
}

// -------- fused structural MLP + output head (one node per thread) --------
__global__ __launch_bounds__(256) void k_final(const float* __restrict__ h,
                                               const float* __restrict__ odeg,
                                               const float* __restrict__ infl,
                                               const unsigned* __restrict__ maxima,
                                               const float* __restrict__ Ws1, const float* __restrict__ bs1,
                                               const float* __restrict__ Ws2, const float* __restrict__ bs2,
                                               const float* __restrict__ Wo1, const float* __restrict__ bo1,
                                               const float* __restrict__ Wo2, const float* __restrict__ bo2,
                                               const float* __restrict__ Wo3, const float* __restrict__ bo3,
                                               float* __restrict__ out, int n) {
    __shared__ float sWs1[96], sbs1[32], sWs2[32 * 64], sbs2[64];
    __shared__ float sWo1[128 * 64], sbo1[64], sWo2[64 * 32], sbo2[32], sWo3[32];
    int t = threadIdx.x;
    for (int i = t; i < 96; i += 256) sWs1[i] = Ws1[i];
    for (int i = t; i < 2048; i += 256) sWs2[i] = Ws2[i];
    for (int i = t; i < 8192; i += 256) sWo1[i] = Wo1[i];
    for (int i = t; i < 2048; i += 256) sWo2[i] = Wo2[i];
    if (t < 32) { sbs1[t] = bs1[t]; sbo2[t] = bo2[t]; sWo3[t] = Wo3[t]; }
    if (t < 64) { sbs2[t] = bs2[t]; sbo1[t] = bo1[t]; }
    __syncthreads();

    int i = blockIdx.x * 256 + t;
    if (i >= n) return;

    float dmax = __uint_as_float(maxima[0]);
    float imax = __uint_as_float(maxima[1]);
    float od = odeg[i];
    float sf0 = (dmax > 0.0f) ? od / dmax : od;
    float fin = infl[i];
    float sf2 = (imax > 0.0f) ? fin / imax : fin;

    float hid[32];
#pragma unroll
    for (int j = 0; j < 32; ++j)
        hid[j] = fmaxf(fmaf(sf0, sWs1[j], fmaf(sf2, sWs1[64 + j], sbs1[j])), 0.0f);

    float o1[64];
#pragma unroll
    for (int c = 0; c < 64; ++c) o1[c] = sbo1[c];

    const float4* hrow = (const float4*)(h + (size_t)i * 64);
    for (int k4 = 0; k4 < 16; ++k4) {
        float4 hv = hrow[k4];
        float hv_[4] = {hv.x, hv.y, hv.z, hv.w};
#pragma unroll
        for (int j = 0; j < 4; ++j) {
            float hk = hv_[j];
            int k = k4 * 4 + j;
#pragma unroll
            for (int c = 0; c < 64; ++c)
                o1[c] = fmaf(hk, sWo1[k * 64 + c], o1[c]);
        }
    }
    for (int k = 0; k < 64; ++k) {
        float sek = sbs2[k];
#pragma unroll
        for (int j = 0; j < 32; ++j) sek = fmaf(hid[j], sWs2[j * 64 + k], sek);
#pragma unroll
        for (int c = 0; c < 64; ++c)
            o1[c] = fmaf(sek, sWo1[(64 + k) * 64 + c], o1[c]);
    }

    float o2[32];
#pragma unroll
    for (int c2 = 0; c2 < 32; ++c2) o2[c2] = sbo2[c2];
#pragma unroll
    for (int c = 0; c < 64; ++c) {
        float v = fmaxf(o1[c], 0.0f);
#pragma unroll
        for (int c2 = 0; c2 < 32; ++c2)
            o2[c2] = fmaf(v, sWo2[c * 32 + c2], o2[c2]);
    }

    float o3 = bo3[0];
#pragma unroll
    for (int c2 = 0; c2 < 32; ++c2)
        o3 = fmaf(fmaxf(o2[c2], 0.0f), sWo3[c2], o3);

    out[i] = 1.0f / (1.0f + __expf(-o3));
}

// ==========================================================================
extern "C" void kernel_launch(void* const* d_in, const int* in_sizes, int n_in,
                              void* d_out, int out_size, void* d_ws, size_t ws_size,
                              hipStream_t stream) {
    const float* x     = (const float*)d_in[0];
    const int*   ei    = (const int*)d_in[1];
    const float* W_in  = (const float*)d_in[2];
    const float* b_in  = (const float*)d_in[3];
    const float* W_gcn = (const float*)d_in[4];
    const float* b_gcn = (const float*)d_in[5];
    const float* gamma = (const float*)d_in[6];
    const float* beta  = (const float*)d_in[7];
    const float* Ws1   = (const float*)d_in[8];
    const float* bs1   = (const float*)d_in[9];
    const float* Ws2   = (const float*)d_in[10];
    const float* bs2   = (const float*)d_in[11];
    const float* Wo1   = (const float*)d_in[12];
    const float* bo1   = (const float*)d_in[13];
    const float* Wo2   = (const float*)d_in[14];
    const float* bo2   = (const float*)d_in[15];
    const float* Wo3   = (const float*)d_in[16];
    const float* bo3   = (const float*)d_in[17];
    float* out = (float*)d_out;

    int n = in_sizes[0] / 128;
    int E = in_sizes[1] / 2;
    const int* row = ei;
    const int* col = ei + E;

    int npass = (n + NBINS - 1) / NBINS;
    int npu = npass * NBINS;                 // padded node range (114688 for n=100K)

    // ---- workspace layout (partial region first; NB shrinks to fit) ----
    auto al = [](size_t v) { return (v + 255) & ~(size_t)255; };
    size_t fixed = al((size_t)(npu + 256) * 4)      // roff
                 + al((size_t)npu * 4)              // cnt
                 + al(1024 * 4)                     // bsum
                 + 3 * al((size_t)npu * 4)          // dis, odeg, infl
                 + al(256)                          // maxima
                 + al((size_t)E * 4)                // esrc
                 + 2 * al((size_t)n * 64 * 4);      // h, hws
    int NB = 128;
    while (NB > 8 && fixed + (size_t)NB * npu * 4 > ws_size) NB >>= 1;
    int chunk = (E + NB - 1) / NB;

    char* p = (char*)d_ws;
    float*          partf  = (float*)p;                 // NB*npu f32 (also u16 view)
    unsigned short* part16 = (unsigned short*)p;        // NB*npu u16 (first half)
    p += al((size_t)NB * npu * 4);
    int* roff = (int*)p;        p += al((size_t)(npu + 256) * 4);
    int* cnt  = (int*)p;        p += al((size_t)npu * 4);
    int* bsum = (int*)p;        p += al(1024 * 4);
    float* dis  = (float*)p;    p += al((size_t)npu * 4);
    float* odeg = (float*)p;    p += al((size_t)npu * 4);
    float* infl = (float*)p;    p += al((size_t)npu * 4);
    unsigned* maxima = (unsigned*)p; p += al(256);
    int* esrc = (int*)p;        p += al((size_t)E * 4);
    float* h   = (float*)p;     p += al((size_t)n * 64 * 4);
    float* hws = (float*)p;

    int gn = (n + 255) / 256;
    int nblk = gn;                            // scan1 blocks

    k_init<<<1, 64, 0, stream>>>(maxima);

    // ---- col-CSR build (no global atomics) ----
    kh_hist<<<NB, TPBH, 0, stream>>>(col, part16, E, chunk, npu, npass);
    kh_reduce_cnt<<<gn, 256, 0, stream>>>(part16, cnt, NB, npu, n);
    k_scan1<<<nblk, 256, 0, stream>>>(cnt, roff, bsum, n);
    k_scan2<<<1, 512, 0, stream>>>(bsum, nblk);
    k_scan3<<<gn, 256, 0, stream>>>(roff, bsum, cnt, dis, n, E);
    kh_prefix<<<gn, 256, 0, stream>>>(part16, NB, npu, n);
    kh_fill<<<NB, TPBH, 0, stream>>>(col, row, roff, part16, esrc, E, chunk, npu, npass);

    // ---- structural stats (row histogram + weighted histogram) ----
    kh_hist<<<NB, TPBH, 0, stream>>>(row, part16, E, chunk, npu, npass);
    kh_reduce_odeg<<<gn, 256, 0, stream>>>(part16, odeg, maxima, NB, npu, n);
    kh_histacc<<<NB, TPBH, 0, stream>>>(row, col, odeg, partf, E, chunk, npu, npass);
    kh_reduce_infl<<<gn, 256, 0, stream>>>(partf, odeg, infl, maxima, NB, npu, n);

    // ---- GNN ----
    k_in_proj<<<(n + 63) / 64, 256, 0, stream>>>(x, W_in, b_in, h, n);

    for (int l = 0; l < 3; ++l) {
        k_gcn_mm<<<(n + 63) / 64, 256, 0, stream>>>(h, W_gcn + (size_t)l * 64 * 64, dis, hws, n);
        k_gather<<<(n + 3) / 4, 256, 0, stream>>>(roff, esrc, hws, dis,
                                                  b_gcn + l * 64, gamma + l * 64, beta + l * 64,
                                                  h, n);
    }

    k_final<<<gn, 256, 0, stream>>>(h, odeg, infl, maxima,
                                    Ws1, bs1, Ws2, bs2, Wo1, bo1, Wo2, bo2, Wo3, bo3,
                                    out, n);
}

// Round 4
// 1067.985 us; speedup vs baseline: 8.4594x; 1.3582x over previous
//
#include <hip/hip_runtime.h>
#include <hip/hip_bf16.h>

#define NBF 16384      // u32/float bins per pass (64 KB LDS)
#define NBP 32768      // packed dual-u16 bins per pass (64 KB LDS)
#define TPBH 512

// ---------------- init: maxima=0 ------------------------------------------
__global__ void k_init(unsigned* __restrict__ maxima) {
    if (threadIdx.x < 2) maxima[threadIdx.x] = 0u;
}

// ---- packed u16 LDS histogram; grid = (chunk_blocks, passes) -------------
__global__ __launch_bounds__(TPBH) void kh_hist(const int* __restrict__ keys,
                                                unsigned short* __restrict__ part,
                                                int E, int chunk, int npu) {
    __shared__ unsigned bins[NBP / 2];        // 64 KB, 2 u16 counters per word
    int b = blockIdx.x, t = threadIdx.x;
    int base = blockIdx.y * NBP;
    int e0 = b * chunk, e1 = min(E, e0 + chunk);
    for (int j = t; j < NBP / 2; j += TPBH) bins[j] = 0u;
    __syncthreads();
    for (int e = e0 + t; e < e1; e += TPBH) {
        int k = keys[e] - base;
        if ((unsigned)k < NBP) atomicAdd(&bins[k >> 1], 1u << ((k & 1) << 4));
    }
    __syncthreads();
    unsigned* dst = (unsigned*)(part + (size_t)b * npu + base);
    for (int j = t; j < NBP / 2; j += TPBH) dst[j] = bins[j];
}

// ---- scan stage 1 (fused partial-reduce): cnt + block-local ex-scan ------
__global__ __launch_bounds__(256) void k_scan1(const unsigned short* __restrict__ part,
                                               int nb, int npu,
                                               int* __restrict__ cnt,
                                               int* __restrict__ roff,
                                               int* __restrict__ bsum, int n) {
    __shared__ int s[256];
    int b = blockIdx.x, t = threadIdx.x;
    int i = b * 256 + t;
    int v = 0;
    if (i < n) {
        for (int k = 0; k < nb; ++k) v += part[(size_t)k * npu + i];
        cnt[i] = v;
    }
    s[t] = v;
    __syncthreads();
    for (int off = 1; off < 256; off <<= 1) {
        int x = (t >= off) ? s[t - off] : 0;
        __syncthreads();
        s[t] += x;
        __syncthreads();
    }
    if (i < n) roff[i] = s[t] - v;
    if (t == 255) bsum[b] = s[255];
}

// ---- scan stage 2: exclusive scan of block sums (1 block, nb<=512) -------
__global__ __launch_bounds__(512) void k_scan2(int* __restrict__ bsum, int nb) {
    __shared__ int s[512];
    int t = threadIdx.x;
    int v = (t < nb) ? bsum[t] : 0;
    s[t] = v;
    __syncthreads();
    for (int off = 1; off < 512; off <<= 1) {
        int x = (t >= off) ? s[t - off] : 0;
        __syncthreads();
        s[t] += x;
        __syncthreads();
    }
    if (t < nb) bsum[t] = s[t] - v;
}

// ---- scan stage 3: finalize roff + dis -----------------------------------
__global__ void k_scan3(int* __restrict__ roff, const int* __restrict__ bsum,
                        const int* __restrict__ cnt, float* __restrict__ dis, int n, int E) {
    int i = blockIdx.x * blockDim.x + threadIdx.x;
    if (i < n) {
        roff[i] += bsum[i >> 8];
        dis[i] = rsqrtf((float)cnt[i] + 1.0f);    // +1 self loop
    }
    if (i == 0) roff[n] = E;
}

// ---- per-node exclusive prefix of u16 partials across blocks (in place) --
__global__ void kh_prefix(unsigned short* __restrict__ part, int nb, int npu, int n) {
    int i = blockIdx.x * blockDim.x + threadIdx.x;
    if (i >= n) return;
    int run = 0;
    for (int b = 0; b < nb; ++b) {
        size_t idx = (size_t)b * npu + i;
        int v = part[idx];
        part[idx] = (unsigned short)run;
        run += v;
    }
}

// ---- CSR fill via LDS cursors; grid = (chunk_blocks, passes) -------------
__global__ __launch_bounds__(TPBH) void kh_fill(const int* __restrict__ col,
                                                const int* __restrict__ row,
                                                const int* __restrict__ roff,
                                                const unsigned short* __restrict__ pref,
                                                int* __restrict__ esrc,
                                                int E, int chunk, int npu) {
    __shared__ unsigned curs[NBF];            // 64 KB
    int b = blockIdx.x, t = threadIdx.x;
    int base = blockIdx.y * NBF;
    int e0 = b * chunk, e1 = min(E, e0 + chunk);
    const unsigned short* pb = pref + (size_t)b * npu + base;
    const int* rb = roff + base;
    for (int j = t; j < NBF; j += TPBH) curs[j] = (unsigned)rb[j] + pb[j];
    __syncthreads();
    for (int e = e0 + t; e < e1; e += TPBH) {
        int c = col[e] - base;
        if ((unsigned)c < NBF) {
            unsigned slot = atomicAdd(&curs[c], 1u);
            esrc[slot] = row[e];
        }
    }
}

// ---- float LDS histogram-accumulate: part[row] += odeg[col]; 2D grid -----
__global__ __launch_bounds__(TPBH) void kh_histacc(const int* __restrict__ row,
                                                   const int* __restrict__ col,
                                                   const float* __restrict__ odeg,
                                                   float* __restrict__ partf,
                                                   int E, int chunk, int npuf) {
    __shared__ float binsf[NBF];              // 64 KB
    int b = blockIdx.x, t = threadIdx.x;
    int base = blockIdx.y * NBF;
    int e0 = b * chunk, e1 = min(E, e0 + chunk);
    for (int j = t; j < NBF; j += TPBH) binsf[j] = 0.f;
    __syncthreads();
    for (int e = e0 + t; e < e1; e += TPBH) {
        int r = row[e] - base;
        if ((unsigned)r < NBF) atomicAdd(&binsf[r], odeg[col[e]]);
    }
    __syncthreads();
    float* dst = partf + (size_t)b * npuf + base;
    for (int j = t; j < NBF; j += TPBH) dst[j] = binsf[j];
}

// ---- reduce u16 partials -> float odeg + dmax ----------------------------
__global__ void kh_reduce_odeg(const unsigned short* __restrict__ part, float* __restrict__ odeg,
                               unsigned* __restrict__ maxima, int nb, int npu, int n) {
    int i = blockIdx.x * blockDim.x + threadIdx.x;
    float od = 0.f;
    if (i < n) {
        int s = 0;
        for (int b = 0; b < nb; ++b) s += part[(size_t)b * npu + i];
        od = (float)s;
        odeg[i] = od;
    }
    for (int off = 32; off > 0; off >>= 1) od = fmaxf(od, __shfl_down(od, off));
    if ((threadIdx.x & 63) == 0) atomicMax(&maxima[0], __float_as_uint(od));
}

// ---- reduce float partials -> infl + imax --------------------------------
__global__ void kh_reduce_infl(const float* __restrict__ partf, const float* __restrict__ odeg,
                               float* __restrict__ infl, unsigned* __restrict__ maxima,
                               int nb, int npuf, int n) {
    int i = blockIdx.x * blockDim.x + threadIdx.x;
    float fin = 0.f;
    if (i < n) {
        float s = 0.f;
        for (int b = 0; b < nb; ++b) s += partf[(size_t)b * npuf + i];
        float od = odeg[i];
        fin = (od > 0.f) ? s / od : 0.f;
        infl[i] = fin;
    }
    for (int off = 32; off > 0; off >>= 1) fin = fmaxf(fin, __shfl_down(fin, off));
    if ((threadIdx.x & 63) == 0) atomicMax(&maxima[1], __float_as_uint(fin));
}

// ---------------- h0 = x @ W_in + b_in  ([N,128]x[128,64]) ----------------
__global__ __launch_bounds__(256) void k_in_proj(const float* __restrict__ x,
                                                 const float* __restrict__ W,
                                                 const float* __restrict__ b,
                                                 float* __restrict__ h, int n) {
    __shared__ float Ws[128 * 64];
    __shared__ float xs[64 * 64];
    int t = threadIdx.x;
    int r0 = blockIdx.x * 64;
    for (int i = t; i < 128 * 64; i += 256) Ws[i] = W[i];

    int c = t & 63, rg = t >> 6;
    float acc[16];
    float bc = b[c];
#pragma unroll
    for (int i = 0; i < 16; ++i) acc[i] = bc;

    for (int half = 0; half < 2; ++half) {
        __syncthreads();
        for (int i = t; i < 64 * 16; i += 256) {
            int rr = i >> 4, k4 = i & 15;
            int r = r0 + rr;
            float4 v = (r < n) ? ((const float4*)x)[(size_t)r * 32 + half * 16 + k4]
                               : make_float4(0.f, 0.f, 0.f, 0.f);
            ((float4*)xs)[i] = v;
        }
        __syncthreads();
        for (int k = 0; k < 64; ++k) {
            float wv = Ws[(half * 64 + k) * 64 + c];
#pragma unroll
            for (int i = 0; i < 16; ++i)
                acc[i] = fmaf(xs[(rg * 16 + i) * 64 + k], wv, acc[i]);
        }
    }
#pragma unroll
    for (int i = 0; i < 16; ++i) {
        int r = r0 + rg * 16 + i;
        if (r < n) h[(size_t)r * 64 + c] = acc[i];
    }
}

// -------- hw = h @ W_gcn; hws = hw * dis[r]  ------------------------------
__global__ __launch_bounds__(256) void k_gcn_mm(const float* __restrict__ h,
                                                const float* __restrict__ Wg,
                                                const float* __restrict__ dis,
                                                float* __restrict__ hws, int n) {
    __shared__ float Ws[64 * 64];
    __shared__ float xs[64 * 64];
    int t = threadIdx.x;
    int r0 = blockIdx.x * 64;
    for (int i = t; i < 64 * 64; i += 256) Ws[i] = Wg[i];
    for (int i = t; i < 64 * 16; i += 256) {
        int rr = i >> 4, k4 = i & 15;
        int r = r0 + rr;
        float4 v = (r < n) ? ((const float4*)h)[(size_t)r * 16 + k4]
                           : make_float4(0.f, 0.f, 0.f, 0.f);
        ((float4*)xs)[i] = v;
    }
    __syncthreads();
    int c = t & 63, rg = t >> 6;
    float acc[16];
#pragma unroll
    for (int i = 0; i < 16; ++i) acc[i] = 0.f;
    for (int k = 0; k < 64; ++k) {
        float wv = Ws[k * 64 + c];
#pragma unroll
        for (int i = 0; i < 16; ++i)
            acc[i] = fmaf(xs[(rg * 16 + i) * 64 + k], wv, acc[i]);
    }
#pragma unroll
    for (int i = 0; i < 16; ++i) {
        int r = r0 + rg * 16 + i;
        if (r < n) hws[(size_t)r * 64 + c] = acc[i] * dis[r];
    }
}

// -------- gather + BN/bias/ReLU epilogue: one wave per node ---------------
__global__ __launch_bounds__(256) void k_gather(const int* __restrict__ roff,
                                                const int* __restrict__ esrc,
                                                const float* __restrict__ hws,
                                                const float* __restrict__ dis,
                                                const float* __restrict__ bg,
                                                const float* __restrict__ gamma,
                                                const float* __restrict__ beta,
                                                float* __restrict__ h, int n) {
    int lane = threadIdx.x & 63;
    int node = blockIdx.x * 4 + (threadIdx.x >> 6);
    if (node >= n) return;
    int beg = roff[node], end = roff[node + 1];
    float acc = hws[(size_t)node * 64 + lane];   // self-loop term (hw*dis)
    int e = beg;
    for (; e + 8 <= end; e += 8) {
        int r0 = esrc[e],     r1 = esrc[e + 1], r2 = esrc[e + 2], r3 = esrc[e + 3];
        int r4 = esrc[e + 4], r5 = esrc[e + 5], r6 = esrc[e + 6], r7 = esrc[e + 7];
        float a0 = hws[(size_t)r0 * 64 + lane];
        float a1 = hws[(size_t)r1 * 64 + lane];
        float a2 = hws[(size_t)r2 * 64 + lane];
        float a3 = hws[(size_t)r3 * 64 + lane];
        float a4 = hws[(size_t)r4 * 64 + lane];
        float a5 = hws[(size_t)r5 * 64 + lane];
        float a6 = hws[(size_t)r6 * 64 + lane];
        float a7 = hws[(size_t)r7 * 64 + lane];
        acc += ((a0 + a1) + (a2 + a3)) + ((a4 + a5) + (a6 + a7));
    }
    for (; e < end; ++e) acc += hws[(size_t)esrc[e] * 64 + lane];
    acc *= dis[node];
    float s = gamma[lane] * rsqrtf(1.0f + 1e-5f);
    h[(size_t)node * 64 + lane] = fmaxf(fmaf(acc + bg[lane], s, beta[lane]), 0.0f);
}

// -------- fused structural MLP + output head (one node per thread) --------
__global__ __launch_bounds__(256) void k_final(const float* __restrict__ h,
                                               const float* __restrict__ odeg,
                                               const float* __restrict__ infl,
                                               const unsigned* __restrict__ maxima,
                                               const float* __restrict__ Ws1, const float* __restrict__ bs1,
                                               const float* __restrict__ Ws2, const float* __restrict__ bs2,
                                               const float* __restrict__ Wo1, const float* __restrict__ bo1,
                                               const float* __restrict__ Wo2, const float* __restrict__ bo2,
                                               const float* __restrict__ Wo3, const float* __restrict__ bo3,
                                               float* __restrict__ out, int n) {
    __shared__ float sWs1[96], sbs1[32], sWs2[32 * 64], sbs2[64];
    __shared__ float sWo1[128 * 64], sbo1[64], sWo2[64 * 32], sbo2[32], sWo3[32];
    int t = threadIdx.x;
    for (int i = t; i < 96; i += 256) sWs1[i] = Ws1[i];
    for (int i = t; i < 2048; i += 256) sWs2[i] = Ws2[i];
    for (int i = t; i < 8192; i += 256) sWo1[i] = Wo1[i];
    for (int i = t; i < 2048; i += 256) sWo2[i] = Wo2[i];
    if (t < 32) { sbs1[t] = bs1[t]; sbo2[t] = bo2[t]; sWo3[t] = Wo3[t]; }
    if (t < 64) { sbs2[t] = bs2[t]; sbo1[t] = bo1[t]; }
    __syncthreads();

    int i = blockIdx.x * 256 + t;
    if (i >= n) return;

    float dmax = __uint_as_float(maxima[0]);
    float imax = __uint_as_float(maxima[1]);
    float od = odeg[i];
    float sf0 = (dmax > 0.0f) ? od / dmax : od;
    float fin = infl[i];
    float sf2 = (imax > 0.0f) ? fin / imax : fin;

    float hid[32];
#pragma unroll
    for (int j = 0; j < 32; ++j)
        hid[j] = fmaxf(fmaf(sf0, sWs1[j], fmaf(sf2, sWs1[64 + j], sbs1[j])), 0.0f);

    float o1[64];
#pragma unroll
    for (int c = 0; c < 64; ++c) o1[c] = sbo1[c];

    const float4* hrow = (const float4*)(h + (size_t)i * 64);
    for (int k4 = 0; k4 < 16; ++k4) {
        float4 hv = hrow[k4];
        float hv_[4] = {hv.x, hv.y, hv.z, hv.w};
#pragma unroll
        for (int j = 0; j < 4; ++j) {
            float hk = hv_[j];
            int k = k4 * 4 + j;
#pragma unroll
            for (int c = 0; c < 64; ++c)
                o1[c] = fmaf(hk, sWo1[k * 64 + c], o1[c]);
        }
    }
    for (int k = 0; k < 64; ++k) {
        float sek = sbs2[k];
#pragma unroll
        for (int j = 0; j < 32; ++j) sek = fmaf(hid[j], sWs2[j * 64 + k], sek);
#pragma unroll
        for (int c = 0; c < 64; ++c)
            o1[c] = fmaf(sek, sWo1[(64 + k) * 64 + c], o1[c]);
    }

    float o2[32];
#pragma unroll
    for (int c2 = 0; c2 < 32; ++c2) o2[c2] = sbo2[c2];
#pragma unroll
    for (int c = 0; c < 64; ++c) {
        float v = fmaxf(o1[c], 0.0f);
#pragma unroll
        for (int c2 = 0; c2 < 32; ++c2)
            o2[c2] = fmaf(v, sWo2[c * 32 + c2], o2[c2]);
    }

    float o3 = bo3[0];
#pragma unroll
    for (int c2 = 0; c2 < 32; ++c2)
        o3 = fmaf(fmaxf(o2[c2], 0.0f), sWo3[c2], o3);

    out[i] = 1.0f / (1.0f + __expf(-o3));
}

// ==========================================================================
extern "C" void kernel_launch(void* const* d_in, const int* in_sizes, int n_in,
                              void* d_out, int out_size, void* d_ws, size_t ws_size,
                              hipStream_t stream) {
    const float* x     = (const float*)d_in[0];
    const int*   ei    = (const int*)d_in[1];
    const float* W_in  = (const float*)d_in[2];
    const float* b_in  = (const float*)d_in[3];
    const float* W_gcn = (const float*)d_in[4];
    const float* b_gcn = (const float*)d_in[5];
    const float* gamma = (const float*)d_in[6];
    const float* beta  = (const float*)d_in[7];
    const float* Ws1   = (const float*)d_in[8];
    const float* bs1   = (const float*)d_in[9];
    const float* Ws2   = (const float*)d_in[10];
    const float* bs2   = (const float*)d_in[11];
    const float* Wo1   = (const float*)d_in[12];
    const float* bo1   = (const float*)d_in[13];
    const float* Wo2   = (const float*)d_in[14];
    const float* bo2   = (const float*)d_in[15];
    const float* Wo3   = (const float*)d_in[16];
    const float* bo3   = (const float*)d_in[17];
    float* out = (float*)d_out;

    int n = in_sizes[0] / 128;
    int E = in_sizes[1] / 2;
    const int* row = ei;
    const int* col = ei + E;

    int npassP = (n + NBP - 1) / NBP;        // packed-hist passes (4 @ n=100K)
    int npassF = (n + NBF - 1) / NBF;        // fill/histacc passes (7 @ n=100K)
    int NPU  = npassP * NBP;                 // u16 partial stride (131072)
    int NPUF = npassF * NBF;                 // float partial stride (114688)

    auto al = [](size_t v) { return (v + 255) & ~(size_t)255; };
    size_t fixed = al((size_t)(NPU + 256) * 4)   // roff
                 + al((size_t)NPU * 4)           // cnt
                 + al(1024 * 4)                  // bsum
                 + 3 * al((size_t)NPU * 4)       // dis, odeg, infl
                 + al(256)                       // maxima
                 + al((size_t)E * 4)             // esrc
                 + 2 * al((size_t)n * 64 * 4);   // h, hws
    int NB = 128;
    auto partBytes = [&](int nb) {
        size_t a = (size_t)nb * NPU * 2, b2 = (size_t)nb * NPUF * 4;
        return a > b2 ? a : b2;
    };
    while (NB > 64 && fixed + partBytes(NB) > ws_size) NB >>= 1;
    int chunk = (E + NB - 1) / NB;           // <= 50000 (u16-safe)

    char* p = (char*)d_ws;
    unsigned short* part16 = (unsigned short*)p;    // [NB][NPU] u16
    float*          partf  = (float*)p;             // [NB][NPUF] f32 (later phase)
    p += al(partBytes(NB));
    int* roff = (int*)p;        p += al((size_t)(NPU + 256) * 4);
    int* cnt  = (int*)p;        p += al((size_t)NPU * 4);
    int* bsum = (int*)p;        p += al(1024 * 4);
    float* dis  = (float*)p;    p += al((size_t)NPU * 4);
    float* odeg = (float*)p;    p += al((size_t)NPU * 4);
    float* infl = (float*)p;    p += al((size_t)NPU * 4);
    unsigned* maxima = (unsigned*)p; p += al(256);
    int* esrc = (int*)p;        p += al((size_t)E * 4);
    float* h   = (float*)p;     p += al((size_t)n * 64 * 4);
    float* hws = (float*)p;

    int gn = (n + 255) / 256;                // 391 blocks (<=512 for scan2)

    k_init<<<1, 64, 0, stream>>>(maxima);

    // ---- col-CSR build (no global atomics) ----
    kh_hist<<<dim3(NB, npassP), TPBH, 0, stream>>>(col, part16, E, chunk, NPU);
    k_scan1<<<gn, 256, 0, stream>>>(part16, NB, NPU, cnt, roff, bsum, n);
    k_scan2<<<1, 512, 0, stream>>>(bsum, gn);
    k_scan3<<<gn, 256, 0, stream>>>(roff, bsum, cnt, dis, n, E);
    kh_prefix<<<gn, 256, 0, stream>>>(part16, NB, NPU, n);
    kh_fill<<<dim3(NB, npassF), TPBH, 0, stream>>>(col, row, roff, part16, esrc, E, chunk, NPU);

    // ---- structural stats ----
    kh_hist<<<dim3(NB, npassP), TPBH, 0, stream>>>(row, part16, E, chunk, NPU);
    kh_reduce_odeg<<<gn, 256, 0, stream>>>(part16, odeg, maxima, NB, NPU, n);
    kh_histacc<<<dim3(NB, npassF), TPBH, 0, stream>>>(row, col, odeg, partf, E, chunk, NPUF);
    kh_reduce_infl<<<gn, 256, 0, stream>>>(partf, odeg, infl, maxima, NB, NPUF, n);

    // ---- GNN ----
    k_in_proj<<<(n + 63) / 64, 256, 0, stream>>>(x, W_in, b_in, h, n);

    for (int l = 0; l < 3; ++l) {
        k_gcn_mm<<<(n + 63) / 64, 256, 0, stream>>>(h, W_gcn + (size_t)l * 64 * 64, dis, hws, n);
        k_gather<<<(n + 3) / 4, 256, 0, stream>>>(roff, esrc, hws, dis,
                                                  b_gcn + l * 64, gamma + l * 64, beta + l * 64,
                                                  h, n);
    }

    k_final<<<gn, 256, 0, stream>>>(h, odeg, infl, maxima,
                                    Ws1, bs1, Ws2, bs2, Wo1, bo1, Wo2, bo2, Wo3, bo3,
                                    out, n);
}

// Round 5
// 915.389 us; speedup vs baseline: 9.8695x; 1.1667x over previous
//
#include <hip/hip_runtime.h>
#include <hip/hip_bf16.h>
#include <hip/hip_fp16.h>

#define NBF 16384      // float bins per pass (64 KB LDS)
#define NBP 32768      // packed dual-u16 bins per pass (64 KB LDS)
#define TPBH 512

// ---------------- init: maxima=0 ------------------------------------------
__global__ void k_init(unsigned* __restrict__ maxima) {
    if (threadIdx.x < 2) maxima[threadIdx.x] = 0u;
}

// ---- packed u16 LDS histogram; grid = (chunk_blocks, passes) -------------
__global__ __launch_bounds__(TPBH) void kh_hist(const int* __restrict__ keys,
                                                unsigned short* __restrict__ part,
                                                int E, int chunk, int npu) {
    __shared__ unsigned bins[NBP / 2];        // 64 KB, 2 u16 counters per word
    int b = blockIdx.x, t = threadIdx.x;
    int base = blockIdx.y * NBP;
    int e0 = b * chunk, e1 = min(E, e0 + chunk);
    for (int j = t; j < NBP / 2; j += TPBH) bins[j] = 0u;
    __syncthreads();
    for (int e = e0 + t; e < e1; e += TPBH) {
        int k = keys[e] - base;
        if ((unsigned)k < NBP) atomicAdd(&bins[k >> 1], 1u << ((k & 1) << 4));
    }
    __syncthreads();
    unsigned* dst = (unsigned*)(part + (size_t)b * npu + base);
    for (int j = t; j < NBP / 2; j += TPBH) dst[j] = bins[j];
}

// ---- scan stage 1 (fused partial-reduce): cnt + block-local ex-scan ------
__global__ __launch_bounds__(256) void k_scan1(const unsigned short* __restrict__ part,
                                               int nb, int npu,
                                               int* __restrict__ cnt,
                                               int* __restrict__ roff,
                                               int* __restrict__ bsum, int n) {
    __shared__ int s[256];
    int b = blockIdx.x, t = threadIdx.x;
    int i = b * 256 + t;
    int v = 0;
    if (i < n) {
        for (int k = 0; k < nb; ++k) v += part[(size_t)k * npu + i];
        cnt[i] = v;
    }
    s[t] = v;
    __syncthreads();
    for (int off = 1; off < 256; off <<= 1) {
        int x = (t >= off) ? s[t - off] : 0;
        __syncthreads();
        s[t] += x;
        __syncthreads();
    }
    if (i < n) roff[i] = s[t] - v;
    if (t == 255) bsum[b] = s[255];
}

// ---- scan stage 2: exclusive scan of block sums (1 block, nb<=512) -------
__global__ __launch_bounds__(512) void k_scan2(int* __restrict__ bsum, int nb) {
    __shared__ int s[512];
    int t = threadIdx.x;
    int v = (t < nb) ? bsum[t] : 0;
    s[t] = v;
    __syncthreads();
    for (int off = 1; off < 512; off <<= 1) {
        int x = (t >= off) ? s[t - off] : 0;
        __syncthreads();
        s[t] += x;
        __syncthreads();
    }
    if (t < nb) bsum[t] = s[t] - v;
}

// ---- scan stage 3: finalize roff + dis -----------------------------------
__global__ void k_scan3(int* __restrict__ roff, const int* __restrict__ bsum,
                        const int* __restrict__ cnt, float* __restrict__ dis, int n, int E) {
    int i = blockIdx.x * blockDim.x + threadIdx.x;
    if (i < n) {
        roff[i] += bsum[i >> 8];
        dis[i] = rsqrtf((float)cnt[i] + 1.0f);    // +1 self loop
    }
    if (i == 0) roff[n] = E;
}

// ---- per-node exclusive prefix of u16 partials across blocks (in place) --
__global__ void kh_prefix(unsigned short* __restrict__ part, int nb, int npu, int n) {
    int i = blockIdx.x * blockDim.x + threadIdx.x;
    if (i >= n) return;
    int run = 0;
    for (int b = 0; b < nb; ++b) {
        size_t idx = (size_t)b * npu + i;
        int v = part[idx];
        part[idx] = (unsigned short)run;
        run += v;
    }
}

// ---- CSR fill via packed-u16 LDS cursors; grid = (chunk_blocks, passes) --
__global__ __launch_bounds__(TPBH) void kh_fill(const int* __restrict__ col,
                                                const int* __restrict__ row,
                                                const int* __restrict__ roff,
                                                const unsigned short* __restrict__ pref,
                                                int* __restrict__ esrc,
                                                int E, int chunk, int npu) {
    __shared__ unsigned curs[NBP / 2];        // 64 KB, 2 u16 local counters/word
    int b = blockIdx.x, t = threadIdx.x;
    int base = blockIdx.y * NBP;
    int e0 = b * chunk, e1 = min(E, e0 + chunk);
    for (int j = t; j < NBP / 2; j += TPBH) curs[j] = 0u;
    __syncthreads();
    const unsigned short* pb = pref + (size_t)b * npu;
    for (int e = e0 + t; e < e1; e += TPBH) {
        int c = col[e], r = row[e];
        int cl = c - base;
        if ((unsigned)cl < NBP) {
            unsigned sh = (cl & 1) << 4;
            unsigned old = atomicAdd(&curs[cl >> 1], 1u << sh);
            unsigned local = (old >> sh) & 0xFFFFu;
            int slot = roff[c] + (int)pb[c] + (int)local;
            esrc[slot] = r;
        }
    }
}

// ---- float LDS histogram-accumulate: part[row] += odeg[col]; 2D grid -----
__global__ __launch_bounds__(TPBH) void kh_histacc(const int* __restrict__ row,
                                                   const int* __restrict__ col,
                                                   const float* __restrict__ odeg,
                                                   float* __restrict__ partf,
                                                   int E, int chunk, int npuf) {
    __shared__ float binsf[NBF];              // 64 KB
    int b = blockIdx.x, t = threadIdx.x;
    int base = blockIdx.y * NBF;
    int e0 = b * chunk, e1 = min(E, e0 + chunk);
    for (int j = t; j < NBF; j += TPBH) binsf[j] = 0.f;
    __syncthreads();
    for (int e = e0 + t; e < e1; e += TPBH) {
        int r = row[e] - base;
        if ((unsigned)r < NBF) atomicAdd(&binsf[r], odeg[col[e]]);
    }
    __syncthreads();
    float* dst = partf + (size_t)b * npuf + base;
    for (int j = t; j < NBF; j += TPBH) dst[j] = binsf[j];
}

// ---- reduce u16 partials -> float odeg + dmax ----------------------------
__global__ void kh_reduce_odeg(const unsigned short* __restrict__ part, float* __restrict__ odeg,
                               unsigned* __restrict__ maxima, int nb, int npu, int n) {
    int i = blockIdx.x * blockDim.x + threadIdx.x;
    float od = 0.f;
    if (i < n) {
        int s = 0;
        for (int b = 0; b < nb; ++b) s += part[(size_t)b * npu + i];
        od = (float)s;
        odeg[i] = od;
    }
    for (int off = 32; off > 0; off >>= 1) od = fmaxf(od, __shfl_down(od, off));
    if ((threadIdx.x & 63) == 0) atomicMax(&maxima[0], __float_as_uint(od));
}

// ---- reduce float partials -> infl + imax --------------------------------
__global__ void kh_reduce_infl(const float* __restrict__ partf, const float* __restrict__ odeg,
                               float* __restrict__ infl, unsigned* __restrict__ maxima,
                               int nb, int npuf, int n) {
    int i = blockIdx.x * blockDim.x + threadIdx.x;
    float fin = 0.f;
    if (i < n) {
        float s = 0.f;
        for (int b = 0; b < nb; ++b) s += partf[(size_t)b * npuf + i];
        float od = odeg[i];
        fin = (od > 0.f) ? s / od : 0.f;
        infl[i] = fin;
    }
    for (int off = 32; off > 0; off >>= 1) fin = fmaxf(fin, __shfl_down(fin, off));
    if ((threadIdx.x & 63) == 0) atomicMax(&maxima[1], __float_as_uint(fin));
}

// ---------------- h0 = x @ W_in + b_in  ([N,128]x[128,64]) ----------------
__global__ __launch_bounds__(256) void k_in_proj(const float* __restrict__ x,
                                                 const float* __restrict__ W,
                                                 const float* __restrict__ b,
                                                 float* __restrict__ h, int n) {
    __shared__ float Ws[128 * 64];
    __shared__ float xs[64 * 64];
    int t = threadIdx.x;
    int r0 = blockIdx.x * 64;
    for (int i = t; i < 128 * 64; i += 256) Ws[i] = W[i];

    int c = t & 63, rg = t >> 6;
    float acc[16];
    float bc = b[c];
#pragma unroll
    for (int i = 0; i < 16; ++i) acc[i] = bc;

    for (int half = 0; half < 2; ++half) {
        __syncthreads();
        for (int i = t; i < 64 * 16; i += 256) {
            int rr = i >> 4, k4 = i & 15;
            int r = r0 + rr;
            float4 v = (r < n) ? ((const float4*)x)[(size_t)r * 32 + half * 16 + k4]
                               : make_float4(0.f, 0.f, 0.f, 0.f);
            ((float4*)xs)[i] = v;
        }
        __syncthreads();
        for (int k = 0; k < 64; ++k) {
            float wv = Ws[(half * 64 + k) * 64 + c];
#pragma unroll
            for (int i = 0; i < 16; ++i)
                acc[i] = fmaf(xs[(rg * 16 + i) * 64 + k], wv, acc[i]);
        }
    }
#pragma unroll
    for (int i = 0; i < 16; ++i) {
        int r = r0 + rg * 16 + i;
        if (r < n) h[(size_t)r * 64 + c] = acc[i];
    }
}

// -------- hw = h @ W_gcn; hws(half) = hw * dis[r] -------------------------
// thread mapping: 2 adjacent features x 8 rows -> __half2 stores
__global__ __launch_bounds__(256) void k_gcn_mm(const float* __restrict__ h,
                                                const float* __restrict__ Wg,
                                                const float* __restrict__ dis,
                                                unsigned* __restrict__ hws, int n) {
    __shared__ float Ws[64 * 64];
    __shared__ float xs[64 * 64];
    int t = threadIdx.x;
    int r0 = blockIdx.x * 64;
    for (int i = t; i < 64 * 64; i += 256) Ws[i] = Wg[i];
    for (int i = t; i < 64 * 16; i += 256) {
        int rr = i >> 4, k4 = i & 15;
        int r = r0 + rr;
        float4 v = (r < n) ? ((const float4*)h)[(size_t)r * 16 + k4]
                           : make_float4(0.f, 0.f, 0.f, 0.f);
        ((float4*)xs)[i] = v;
    }
    __syncthreads();
    int c2 = (t & 31) << 1, rg = t >> 5;     // 2 features, 8 row-groups x 8 rows
    float a0[8], a1[8];
#pragma unroll
    for (int i = 0; i < 8; ++i) { a0[i] = 0.f; a1[i] = 0.f; }
    for (int k = 0; k < 64; ++k) {
        float w0 = Ws[k * 64 + c2];
        float w1 = Ws[k * 64 + c2 + 1];
#pragma unroll
        for (int i = 0; i < 8; ++i) {
            float xv = xs[(rg * 8 + i) * 64 + k];
            a0[i] = fmaf(xv, w0, a0[i]);
            a1[i] = fmaf(xv, w1, a1[i]);
        }
    }
#pragma unroll
    for (int i = 0; i < 8; ++i) {
        int r = r0 + rg * 8 + i;
        if (r < n) {
            float d = dis[r];
            __half2 hv = __floats2half2_rn(a0[i] * d, a1[i] * d);
            hws[(size_t)r * 32 + (t & 31)] = *(unsigned*)&hv;
        }
    }
}

// -------- gather + BN/bias/ReLU: 4 nodes/wave, 16 lanes/node, 4 feat/lane -
__global__ __launch_bounds__(256) void k_gather(const int* __restrict__ roff,
                                                const int* __restrict__ esrc,
                                                const uint2* __restrict__ hws, // half[64] rows as 16x uint2
                                                const float* __restrict__ dis,
                                                const float* __restrict__ bg,
                                                const float* __restrict__ gamma,
                                                const float* __restrict__ beta,
                                                float* __restrict__ h, int n) {
    int t = threadIdx.x;
    int node = blockIdx.x * 16 + (t >> 4);   // 16 nodes per block
    int fl = t & 15;                          // uint2 index within row (4 feats)
    if (node >= n) return;

    int beg = roff[node], end = roff[node + 1];
    float acc0 = 0.f, acc1 = 0.f, acc2 = 0.f, acc3 = 0.f;
    union { unsigned u; __half2 h2; } cv;

    // self-loop term
    {
        uint2 a = hws[(size_t)node * 16 + fl];
        cv.u = a.x; float2 f = __half22float2(cv.h2); acc0 += f.x; acc1 += f.y;
        cv.u = a.y; f = __half22float2(cv.h2);        acc2 += f.x; acc3 += f.y;
    }
    int e = beg;
    for (; e + 2 <= end; e += 2) {
        int r0 = esrc[e], r1 = esrc[e + 1];
        uint2 a = hws[(size_t)r0 * 16 + fl];
        uint2 b = hws[(size_t)r1 * 16 + fl];
        cv.u = a.x; float2 f = __half22float2(cv.h2); acc0 += f.x; acc1 += f.y;
        cv.u = a.y; f = __half22float2(cv.h2);        acc2 += f.x; acc3 += f.y;
        cv.u = b.x; f = __half22float2(cv.h2);        acc0 += f.x; acc1 += f.y;
        cv.u = b.y; f = __half22float2(cv.h2);        acc2 += f.x; acc3 += f.y;
    }
    if (e < end) {
        uint2 a = hws[(size_t)esrc[e] * 16 + fl];
        cv.u = a.x; float2 f = __half22float2(cv.h2); acc0 += f.x; acc1 += f.y;
        cv.u = a.y; f = __half22float2(cv.h2);        acc2 += f.x; acc3 += f.y;
    }

    float d = dis[node];
    float inv = rsqrtf(1.0f + 1e-5f);
    float4 g4 = ((const float4*)gamma)[fl];
    float4 b4 = ((const float4*)beta)[fl];
    float4 bg4 = ((const float4*)bg)[fl];
    float4 o;
    o.x = fmaxf(fmaf(acc0 * d + bg4.x, g4.x * inv, b4.x), 0.0f);
    o.y = fmaxf(fmaf(acc1 * d + bg4.y, g4.y * inv, b4.y), 0.0f);
    o.z = fmaxf(fmaf(acc2 * d + bg4.z, g4.z * inv, b4.z), 0.0f);
    o.w = fmaxf(fmaf(acc3 * d + bg4.w, g4.w * inv, b4.w), 0.0f);
    ((float4*)h)[(size_t)node * 16 + fl] = o;
}

// -------- fused structural MLP + output head (one node per thread) --------
__global__ __launch_bounds__(256) void k_final(const float* __restrict__ h,
                                               const float* __restrict__ odeg,
                                               const float* __restrict__ infl,
                                               const unsigned* __restrict__ maxima,
                                               const float* __restrict__ Ws1, const float* __restrict__ bs1,
                                               const float* __restrict__ Ws2, const float* __restrict__ bs2,
                                               const float* __restrict__ Wo1, const float* __restrict__ bo1,
                                               const float* __restrict__ Wo2, const float* __restrict__ bo2,
                                               const float* __restrict__ Wo3, const float* __restrict__ bo3,
                                               float* __restrict__ out, int n) {
    __shared__ float sWs1[96], sbs1[32], sWs2[32 * 64], sbs2[64];
    __shared__ float sWo1[128 * 64], sbo1[64], sWo2[64 * 32], sbo2[32], sWo3[32];
    int t = threadIdx.x;
    for (int i = t; i < 96; i += 256) sWs1[i] = Ws1[i];
    for (int i = t; i < 2048; i += 256) sWs2[i] = Ws2[i];
    for (int i = t; i < 8192; i += 256) sWo1[i] = Wo1[i];
    for (int i = t; i < 2048; i += 256) sWo2[i] = Wo2[i];
    if (t < 32) { sbs1[t] = bs1[t]; sbo2[t] = bo2[t]; sWo3[t] = Wo3[t]; }
    if (t < 64) { sbs2[t] = bs2[t]; sbo1[t] = bo1[t]; }
    __syncthreads();

    int i = blockIdx.x * 256 + t;
    if (i >= n) return;

    float dmax = __uint_as_float(maxima[0]);
    float imax = __uint_as_float(maxima[1]);
    float od = odeg[i];
    float sf0 = (dmax > 0.0f) ? od / dmax : od;
    float fin = infl[i];
    float sf2 = (imax > 0.0f) ? fin / imax : fin;

    float hid[32];
#pragma unroll
    for (int j = 0; j < 32; ++j)
        hid[j] = fmaxf(fmaf(sf0, sWs1[j], fmaf(sf2, sWs1[64 + j], sbs1[j])), 0.0f);

    float o1[64];
#pragma unroll
    for (int c = 0; c < 64; ++c) o1[c] = sbo1[c];

    const float4* hrow = (const float4*)(h + (size_t)i * 64);
    for (int k4 = 0; k4 < 16; ++k4) {
        float4 hv = hrow[k4];
        float hv_[4] = {hv.x, hv.y, hv.z, hv.w};
#pragma unroll
        for (int j = 0; j < 4; ++j) {
            float hk = hv_[j];
            int k = k4 * 4 + j;
#pragma unroll
            for (int c = 0; c < 64; ++c)
                o1[c] = fmaf(hk, sWo1[k * 64 + c], o1[c]);
        }
    }
    for (int k = 0; k < 64; ++k) {
        float sek = sbs2[k];
#pragma unroll
        for (int j = 0; j < 32; ++j) sek = fmaf(hid[j], sWs2[j * 64 + k], sek);
#pragma unroll
        for (int c = 0; c < 64; ++c)
            o1[c] = fmaf(sek, sWo1[(64 + k) * 64 + c], o1[c]);
    }

    float o2[32];
#pragma unroll
    for (int c2 = 0; c2 < 32; ++c2) o2[c2] = sbo2[c2];
#pragma unroll
    for (int c = 0; c < 64; ++c) {
        float v = fmaxf(o1[c], 0.0f);
#pragma unroll
        for (int c2 = 0; c2 < 32; ++c2)
            o2[c2] = fmaf(v, sWo2[c * 32 + c2], o2[c2]);
    }

    float o3 = bo3[0];
#pragma unroll
    for (int c2 = 0; c2 < 32; ++c2)
        o3 = fmaf(fmaxf(o2[c2], 0.0f), sWo3[c2], o3);

    out[i] = 1.0f / (1.0f + __expf(-o3));
}

// ==========================================================================
extern "C" void kernel_launch(void* const* d_in, const int* in_sizes, int n_in,
                              void* d_out, int out_size, void* d_ws, size_t ws_size,
                              hipStream_t stream) {
    const float* x     = (const float*)d_in[0];
    const int*   ei    = (const int*)d_in[1];
    const float* W_in  = (const float*)d_in[2];
    const float* b_in  = (const float*)d_in[3];
    const float* W_gcn = (const float*)d_in[4];
    const float* b_gcn = (const float*)d_in[5];
    const float* gamma = (const float*)d_in[6];
    const float* beta  = (const float*)d_in[7];
    const float* Ws1   = (const float*)d_in[8];
    const float* bs1   = (const float*)d_in[9];
    const float* Ws2   = (const float*)d_in[10];
    const float* bs2   = (const float*)d_in[11];
    const float* Wo1   = (const float*)d_in[12];
    const float* bo1   = (const float*)d_in[13];
    const float* Wo2   = (const float*)d_in[14];
    const float* bo2   = (const float*)d_in[15];
    const float* Wo3   = (const float*)d_in[16];
    const float* bo3   = (const float*)d_in[17];
    float* out = (float*)d_out;

    int n = in_sizes[0] / 128;
    int E = in_sizes[1] / 2;
    const int* row = ei;
    const int* col = ei + E;

    int npassP = (n + NBP - 1) / NBP;        // packed passes (4 @ n=100K)
    int npassF = (n + NBF - 1) / NBF;        // float histacc passes (7)
    int NPU  = npassP * NBP;                 // u16 partial stride (131072)
    int NPUF = npassF * NBF;                 // float partial stride (114688)

    auto al = [](size_t v) { return (v + 255) & ~(size_t)255; };
    size_t fixed = al((size_t)(NPU + 256) * 4)   // roff
                 + al((size_t)NPU * 4)           // cnt
                 + al(1024 * 4)                  // bsum
                 + 3 * al((size_t)NPU * 4)       // dis, odeg, infl
                 + al(256)                       // maxima
                 + al((size_t)E * 4)             // esrc
                 + al((size_t)n * 64 * 4)        // h (f32)
                 + al((size_t)n * 64 * 2);       // hws (f16)
    int NB = 128;
    auto partBytes = [&](int nb) {
        size_t a = (size_t)nb * NPU * 2, b2 = (size_t)nb * NPUF * 4;
        return a > b2 ? a : b2;
    };
    while (NB > 32 && fixed + partBytes(NB) > ws_size) NB >>= 1;
    int chunk = (E + NB - 1) / NB;

    char* p = (char*)d_ws;
    unsigned short* part16 = (unsigned short*)p;    // [NB][NPU] u16
    float*          partf  = (float*)p;             // [NB][NPUF] f32 (later phase)
    p += al(partBytes(NB));
    int* roff = (int*)p;        p += al((size_t)(NPU + 256) * 4);
    int* cnt  = (int*)p;        p += al((size_t)NPU * 4);
    int* bsum = (int*)p;        p += al(1024 * 4);
    float* dis  = (float*)p;    p += al((size_t)NPU * 4);
    float* odeg = (float*)p;    p += al((size_t)NPU * 4);
    float* infl = (float*)p;    p += al((size_t)NPU * 4);
    unsigned* maxima = (unsigned*)p; p += al(256);
    int* esrc = (int*)p;        p += al((size_t)E * 4);
    float* h   = (float*)p;     p += al((size_t)n * 64 * 4);
    unsigned* hws = (unsigned*)p;                   // half2-packed [n][32]

    int gn = (n + 255) / 256;                // <=512 for scan2

    k_init<<<1, 64, 0, stream>>>(maxima);

    // ---- col-CSR build (no global atomics) ----
    kh_hist<<<dim3(NB, npassP), TPBH, 0, stream>>>(col, part16, E, chunk, NPU);
    k_scan1<<<gn, 256, 0, stream>>>(part16, NB, NPU, cnt, roff, bsum, n);
    k_scan2<<<1, 512, 0, stream>>>(bsum, gn);
    k_scan3<<<gn, 256, 0, stream>>>(roff, bsum, cnt, dis, n, E);
    kh_prefix<<<gn, 256, 0, stream>>>(part16, NB, NPU, n);
    kh_fill<<<dim3(NB, npassP), TPBH, 0, stream>>>(col, row, roff, part16, esrc, E, chunk, NPU);

    // ---- structural stats ----
    kh_hist<<<dim3(NB, npassP), TPBH, 0, stream>>>(row, part16, E, chunk, NPU);
    kh_reduce_odeg<<<gn, 256, 0, stream>>>(part16, odeg, maxima, NB, NPU, n);
    kh_histacc<<<dim3(NB, npassF), TPBH, 0, stream>>>(row, col, odeg, partf, E, chunk, NPUF);
    kh_reduce_infl<<<gn, 256, 0, stream>>>(partf, odeg, infl, maxima, NB, NPUF, n);

    // ---- GNN ----
    k_in_proj<<<(n + 63) / 64, 256, 0, stream>>>(x, W_in, b_in, h, n);

    for (int l = 0; l < 3; ++l) {
        k_gcn_mm<<<(n + 63) / 64, 256, 0, stream>>>(h, W_gcn + (size_t)l * 64 * 64, dis, hws, n);
        k_gather<<<(n + 15) / 16, 256, 0, stream>>>(roff, esrc, (const uint2*)hws, dis,
                                                    b_gcn + l * 64, gamma + l * 64, beta + l * 64,
                                                    h, n);
    }

    k_final<<<gn, 256, 0, stream>>>(h, odeg, infl, maxima,
                                    Ws1, bs1, Ws2, bs2, Wo1, bo1, Wo2, bo2, Wo3, bo3,
                                    out, n);
}

// Round 6
// 799.749 us; speedup vs baseline: 11.2966x; 1.1446x over previous
//
#include <hip/hip_runtime.h>
#include <hip/hip_bf16.h>
#include <hip/hip_fp16.h>

#define NBU8 65536     // u8-packed bins per pass (64 KB LDS)
#define NB16 32768     // u16-packed bins per pass (64 KB LDS)
#define TPBH 1024

// ---------------- init: maxima=0 ------------------------------------------
__global__ void k_init(unsigned* __restrict__ maxima) {
    if (threadIdx.x < 2) maxima[threadIdx.x] = 0u;
}

// ---- u8-packed LDS histogram; grid = (chunk_blocks, passes) --------------
__global__ __launch_bounds__(TPBH) void kh_hist(const int* __restrict__ keys,
                                                unsigned char* __restrict__ part,
                                                int E, int chunk, int npu) {
    __shared__ unsigned bins[NBU8 / 4];       // 64 KB, 4 u8 counters per word
    int b = blockIdx.x, t = threadIdx.x;
    int base = blockIdx.y * NBU8;
    int e0 = b * chunk, e1 = min(E, e0 + chunk);
    for (int j = t; j < NBU8 / 4; j += TPBH) bins[j] = 0u;
    __syncthreads();
    for (int e = e0 + t; e < e1; e += TPBH) {
        int k = keys[e] - base;
        if ((unsigned)k < NBU8) atomicAdd(&bins[k >> 2], 1u << ((k & 3) << 3));
    }
    __syncthreads();
    unsigned* dst = (unsigned*)(part + (size_t)b * npu + base);
    for (int j = t; j < NBU8 / 4; j += TPBH) dst[j] = bins[j];
}

// ---- scan stage 1 (fused u8-partial reduce): cnt + block-local ex-scan ---
__global__ __launch_bounds__(256) void k_scan1(const unsigned char* __restrict__ part,
                                               int nb, int npu,
                                               int* __restrict__ cnt,
                                               int* __restrict__ roff,
                                               int* __restrict__ bsum, int n) {
    __shared__ int s[256];
    int b = blockIdx.x, t = threadIdx.x;
    int i = b * 256 + t;
    int v = 0;
    if (i < n) {
        for (int k = 0; k < nb; ++k) v += part[(size_t)k * npu + i];
        cnt[i] = v;
    }
    s[t] = v;
    __syncthreads();
    for (int off = 1; off < 256; off <<= 1) {
        int x = (t >= off) ? s[t - off] : 0;
        __syncthreads();
        s[t] += x;
        __syncthreads();
    }
    if (i < n) roff[i] = s[t] - v;
    if (t == 255) bsum[b] = s[255];
}

// ---- scan stage 2: exclusive scan of block sums (1 block, nb<=512) -------
__global__ __launch_bounds__(512) void k_scan2(int* __restrict__ bsum, int nb) {
    __shared__ int s[512];
    int t = threadIdx.x;
    int v = (t < nb) ? bsum[t] : 0;
    s[t] = v;
    __syncthreads();
    for (int off = 1; off < 512; off <<= 1) {
        int x = (t >= off) ? s[t - off] : 0;
        __syncthreads();
        s[t] += x;
        __syncthreads();
    }
    if (t < nb) bsum[t] = s[t] - v;
}

// ---- scan stage 3: finalize roff + dis -----------------------------------
__global__ void k_scan3(int* __restrict__ roff, const int* __restrict__ bsum,
                        const int* __restrict__ cnt, float* __restrict__ dis, int n, int E) {
    int i = blockIdx.x * blockDim.x + threadIdx.x;
    if (i < n) {
        roff[i] += bsum[i >> 8];
        dis[i] = rsqrtf((float)cnt[i] + 1.0f);    // +1 self loop
    }
    if (i == 0) roff[n] = E;
}

// ---- per-node exclusive prefix of u8 partials, XCD-grouped block order ---
__global__ void kh_prefix(unsigned char* __restrict__ part, int nb, int npu, int n) {
    int i = blockIdx.x * blockDim.x + threadIdx.x;
    if (i >= n) return;
    int run = 0;
    // iterate blocks grouped by XCD (b%8) so CSR slots from one XCD are adjacent
    for (int g = 0; g < 8; ++g) {
        for (int b = g; b < nb; b += 8) {
            size_t idx = (size_t)b * npu + i;
            int v = part[idx];
            part[idx] = (unsigned char)run;
            run += v;
        }
    }
}

// ---- CSR fill via u8-packed LDS cursors; grid = (chunk_blocks, passes) ---
__global__ __launch_bounds__(TPBH) void kh_fill(const int* __restrict__ col,
                                                const int* __restrict__ row,
                                                const int* __restrict__ roff,
                                                const unsigned char* __restrict__ pref,
                                                int* __restrict__ esrc,
                                                int E, int chunk, int npu) {
    __shared__ unsigned curs[NBU8 / 4];       // 64 KB, 4 u8 local counters/word
    int b = blockIdx.x, t = threadIdx.x;
    int base = blockIdx.y * NBU8;
    int e0 = b * chunk, e1 = min(E, e0 + chunk);
    for (int j = t; j < NBU8 / 4; j += TPBH) curs[j] = 0u;
    __syncthreads();
    const unsigned char* pb = pref + (size_t)b * npu;
    for (int e = e0 + t; e < e1; e += TPBH) {
        int c = col[e], r = row[e];
        int cl = c - base;
        if ((unsigned)cl < NBU8) {
            unsigned sh = (cl & 3) << 3;
            unsigned old = atomicAdd(&curs[cl >> 2], 1u << sh);
            unsigned local = (old >> sh) & 0xFFu;
            int slot = roff[c] + (int)pb[c] + (int)local;
            esrc[slot] = r;
        }
    }
}

// ---- u16 integer LDS histogram-accumulate: part[row] += odeg_i[col] ------
__global__ __launch_bounds__(TPBH) void kh_histacc(const int* __restrict__ row,
                                                   const int* __restrict__ col,
                                                   const int* __restrict__ odeg_i,
                                                   unsigned short* __restrict__ part,
                                                   int E, int chunk, int npu) {
    __shared__ unsigned bins[NB16 / 2];       // 64 KB, 2 u16 sums per word
    int b = blockIdx.x, t = threadIdx.x;
    int base = blockIdx.y * NB16;
    int e0 = b * chunk, e1 = min(E, e0 + chunk);
    for (int j = t; j < NB16 / 2; j += TPBH) bins[j] = 0u;
    __syncthreads();
    for (int e = e0 + t; e < e1; e += TPBH) {
        int r = row[e] - base;
        if ((unsigned)r < NB16)
            atomicAdd(&bins[r >> 1], (unsigned)odeg_i[col[e]] << ((r & 1) << 4));
    }
    __syncthreads();
    unsigned* dst = (unsigned*)(part + (size_t)b * npu + base);
    for (int j = t; j < NB16 / 2; j += TPBH) dst[j] = bins[j];
}

// ---- reduce u8 partials -> float odeg + int odeg + dmax ------------------
__global__ void kh_reduce_odeg(const unsigned char* __restrict__ part,
                               float* __restrict__ odeg, int* __restrict__ odeg_i,
                               unsigned* __restrict__ maxima, int nb, int npu, int n) {
    int i = blockIdx.x * blockDim.x + threadIdx.x;
    float od = 0.f;
    if (i < n) {
        int s = 0;
        for (int b = 0; b < nb; ++b) s += part[(size_t)b * npu + i];
        od = (float)s;
        odeg[i] = od;
        odeg_i[i] = s;
    }
    for (int off = 32; off > 0; off >>= 1) od = fmaxf(od, __shfl_down(od, off));
    if ((threadIdx.x & 63) == 0) atomicMax(&maxima[0], __float_as_uint(od));
}

// ---- reduce u16 partials -> infl + imax ----------------------------------
__global__ void kh_reduce_infl(const unsigned short* __restrict__ part,
                               const float* __restrict__ odeg,
                               float* __restrict__ infl, unsigned* __restrict__ maxima,
                               int nb, int npu, int n) {
    int i = blockIdx.x * blockDim.x + threadIdx.x;
    float fin = 0.f;
    if (i < n) {
        int s = 0;
        for (int b = 0; b < nb; ++b) s += part[(size_t)b * npu + i];
        float od = odeg[i];
        fin = (od > 0.f) ? (float)s / od : 0.f;
        infl[i] = fin;
    }
    for (int off = 32; off > 0; off >>= 1) fin = fmaxf(fin, __shfl_down(fin, off));
    if ((threadIdx.x & 63) == 0) atomicMax(&maxima[1], __float_as_uint(fin));
}

// ---------------- h0 = x @ W_in + b_in  ([N,128]x[128,64]) ----------------
__global__ __launch_bounds__(256) void k_in_proj(const float* __restrict__ x,
                                                 const float* __restrict__ W,
                                                 const float* __restrict__ b,
                                                 float* __restrict__ h, int n) {
    __shared__ alignas(16) float Ws[128 * 64];
    __shared__ alignas(16) float xs[64 * 64];
    int t = threadIdx.x;
    int r0 = blockIdx.x * 64;
    for (int i = t; i < 128 * 64; i += 256) Ws[i] = W[i];

    int c = t & 63, rg = t >> 6;
    float acc[16];
    float bc = b[c];
#pragma unroll
    for (int i = 0; i < 16; ++i) acc[i] = bc;

    const float4* xs4 = (const float4*)xs;
    for (int half = 0; half < 2; ++half) {
        __syncthreads();
        for (int i = t; i < 64 * 16; i += 256) {
            int rr = i >> 4, k4 = i & 15;
            int r = r0 + rr;
            float4 v = (r < n) ? ((const float4*)x)[(size_t)r * 32 + half * 16 + k4]
                               : make_float4(0.f, 0.f, 0.f, 0.f);
            ((float4*)xs)[i] = v;
        }
        __syncthreads();
        for (int k4 = 0; k4 < 16; ++k4) {
            int kk = half * 64 + k4 * 4;
            float w0 = Ws[(kk + 0) * 64 + c];
            float w1 = Ws[(kk + 1) * 64 + c];
            float w2 = Ws[(kk + 2) * 64 + c];
            float w3 = Ws[(kk + 3) * 64 + c];
#pragma unroll
            for (int i = 0; i < 16; ++i) {
                float4 xv = xs4[(rg * 16 + i) * 16 + k4];
                acc[i] = fmaf(xv.x, w0, fmaf(xv.y, w1, fmaf(xv.z, w2, fmaf(xv.w, w3, acc[i]))));
            }
        }
    }
#pragma unroll
    for (int i = 0; i < 16; ++i) {
        int r = r0 + rg * 16 + i;
        if (r < n) h[(size_t)r * 64 + c] = acc[i];
    }
}

// -------- hw = h @ W_gcn; hws(half2) = hw * dis[r] ------------------------
__global__ __launch_bounds__(256) void k_gcn_mm(const float* __restrict__ h,
                                                const float* __restrict__ Wg,
                                                const float* __restrict__ dis,
                                                unsigned* __restrict__ hws, int n) {
    __shared__ alignas(16) float Ws[64 * 64];
    __shared__ alignas(16) float xs[64 * 64];
    int t = threadIdx.x;
    int r0 = blockIdx.x * 64;
    for (int i = t; i < 64 * 64; i += 256) Ws[i] = Wg[i];
    for (int i = t; i < 64 * 16; i += 256) {
        int rr = i >> 4, k4 = i & 15;
        int r = r0 + rr;
        float4 v = (r < n) ? ((const float4*)h)[(size_t)r * 16 + k4]
                           : make_float4(0.f, 0.f, 0.f, 0.f);
        ((float4*)xs)[i] = v;
    }
    __syncthreads();
    int c2 = (t & 31) << 1, rg = t >> 5;     // 2 features x (8 row-groups x 8 rows)
    const float4* xs4 = (const float4*)xs;
    float a0[8], a1[8];
#pragma unroll
    for (int i = 0; i < 8; ++i) { a0[i] = 0.f; a1[i] = 0.f; }
    for (int k4 = 0; k4 < 16; ++k4) {
        float wA0 = Ws[(k4 * 4 + 0) * 64 + c2],     wB0 = Ws[(k4 * 4 + 0) * 64 + c2 + 1];
        float wA1 = Ws[(k4 * 4 + 1) * 64 + c2],     wB1 = Ws[(k4 * 4 + 1) * 64 + c2 + 1];
        float wA2 = Ws[(k4 * 4 + 2) * 64 + c2],     wB2 = Ws[(k4 * 4 + 2) * 64 + c2 + 1];
        float wA3 = Ws[(k4 * 4 + 3) * 64 + c2],     wB3 = Ws[(k4 * 4 + 3) * 64 + c2 + 1];
#pragma unroll
        for (int i = 0; i < 8; ++i) {
            float4 xv = xs4[(rg * 8 + i) * 16 + k4];
            a0[i] = fmaf(xv.x, wA0, fmaf(xv.y, wA1, fmaf(xv.z, wA2, fmaf(xv.w, wA3, a0[i]))));
            a1[i] = fmaf(xv.x, wB0, fmaf(xv.y, wB1, fmaf(xv.z, wB2, fmaf(xv.w, wB3, a1[i]))));
        }
    }
#pragma unroll
    for (int i = 0; i < 8; ++i) {
        int r = r0 + rg * 8 + i;
        if (r < n) {
            float d = dis[r];
            __half2 hv = __floats2half2_rn(a0[i] * d, a1[i] * d);
            hws[(size_t)r * 32 + (t & 31)] = *(unsigned*)&hv;
        }
    }
}

// -------- gather + BN/bias/ReLU: 16 lanes/node, 4 feats/lane --------------
__global__ __launch_bounds__(256) void k_gather(const int* __restrict__ roff,
                                                const int* __restrict__ esrc,
                                                const uint2* __restrict__ hws,
                                                const float* __restrict__ dis,
                                                const float* __restrict__ bg,
                                                const float* __restrict__ gamma,
                                                const float* __restrict__ beta,
                                                float* __restrict__ h, int n) {
    int t = threadIdx.x;
    int node = blockIdx.x * 16 + (t >> 4);
    int fl = t & 15;
    if (node >= n) return;

    int beg = roff[node], end = roff[node + 1];
    float acc0 = 0.f, acc1 = 0.f, acc2 = 0.f, acc3 = 0.f;
    union { unsigned u; __half2 h2; } cv;
#define ACC(a) { cv.u = (a).x; float2 f = __half22float2(cv.h2); acc0 += f.x; acc1 += f.y; \
                 cv.u = (a).y; f = __half22float2(cv.h2);        acc2 += f.x; acc3 += f.y; }
    {
        uint2 a = hws[(size_t)node * 16 + fl];   // self-loop term
        ACC(a)
    }
    int e = beg;
    for (; e + 4 <= end; e += 4) {
        int r0 = esrc[e], r1 = esrc[e + 1], r2 = esrc[e + 2], r3 = esrc[e + 3];
        uint2 a = hws[(size_t)r0 * 16 + fl];
        uint2 b = hws[(size_t)r1 * 16 + fl];
        uint2 c = hws[(size_t)r2 * 16 + fl];
        uint2 d = hws[(size_t)r3 * 16 + fl];
        ACC(a) ACC(b) ACC(c) ACC(d)
    }
    for (; e < end; ++e) {
        uint2 a = hws[(size_t)esrc[e] * 16 + fl];
        ACC(a)
    }
#undef ACC
    float d = dis[node];
    float inv = rsqrtf(1.0f + 1e-5f);
    float4 g4 = ((const float4*)gamma)[fl];
    float4 b4 = ((const float4*)beta)[fl];
    float4 bg4 = ((const float4*)bg)[fl];
    float4 o;
    o.x = fmaxf(fmaf(acc0 * d + bg4.x, g4.x * inv, b4.x), 0.0f);
    o.y = fmaxf(fmaf(acc1 * d + bg4.y, g4.y * inv, b4.y), 0.0f);
    o.z = fmaxf(fmaf(acc2 * d + bg4.z, g4.z * inv, b4.z), 0.0f);
    o.w = fmaxf(fmaf(acc3 * d + bg4.w, g4.w * inv, b4.w), 0.0f);
    ((float4*)h)[(size_t)node * 16 + fl] = o;
}

// -------- fused structural MLP + output head (one node per thread) --------
__global__ __launch_bounds__(256) void k_final(const float* __restrict__ h,
                                               const float* __restrict__ odeg,
                                               const float* __restrict__ infl,
                                               const unsigned* __restrict__ maxima,
                                               const float* __restrict__ Ws1, const float* __restrict__ bs1,
                                               const float* __restrict__ Ws2, const float* __restrict__ bs2,
                                               const float* __restrict__ Wo1, const float* __restrict__ bo1,
                                               const float* __restrict__ Wo2, const float* __restrict__ bo2,
                                               const float* __restrict__ Wo3, const float* __restrict__ bo3,
                                               float* __restrict__ out, int n) {
    __shared__ alignas(16) float sWs1[96], sbs1[32], sWs2T[64 * 32], sbs2[64];
    __shared__ alignas(16) float sWo1[128 * 64], sbo1[64], sWo2[64 * 32], sbo2[32], sWo3[32];
    int t = threadIdx.x;
    for (int i = t; i < 96; i += 256) sWs1[i] = Ws1[i];
    for (int i = t; i < 2048; i += 256) {            // transpose W_s2: [32][64] -> [64][32]
        int j = i >> 6, k = i & 63;
        sWs2T[k * 32 + j] = Ws2[i];
    }
    for (int i = t; i < 8192; i += 256) sWo1[i] = Wo1[i];
    for (int i = t; i < 2048; i += 256) sWo2[i] = Wo2[i];
    if (t < 32) { sbs1[t] = bs1[t]; sbo2[t] = bo2[t]; sWo3[t] = Wo3[t]; }
    if (t < 64) { sbs2[t] = bs2[t]; sbo1[t] = bo1[t]; }
    __syncthreads();

    int i = blockIdx.x * 256 + t;
    if (i >= n) return;

    float dmax = __uint_as_float(maxima[0]);
    float imax = __uint_as_float(maxima[1]);
    float od = odeg[i];
    float sf0 = (dmax > 0.0f) ? od / dmax : od;
    float fin = infl[i];
    float sf2 = (imax > 0.0f) ? fin / imax : fin;

    float hid[32];
#pragma unroll
    for (int j = 0; j < 32; ++j)
        hid[j] = fmaxf(fmaf(sf0, sWs1[j], fmaf(sf2, sWs1[64 + j], sbs1[j])), 0.0f);

    float o1[64];
    const float4* sbo1_4 = (const float4*)sbo1;
#pragma unroll
    for (int c4 = 0; c4 < 16; ++c4) {
        float4 v = sbo1_4[c4];
        o1[c4 * 4] = v.x; o1[c4 * 4 + 1] = v.y; o1[c4 * 4 + 2] = v.z; o1[c4 * 4 + 3] = v.w;
    }

    const float4* sWo1_4 = (const float4*)sWo1;
    const float4* hrow = (const float4*)(h + (size_t)i * 64);
    for (int k4 = 0; k4 < 16; ++k4) {
        float4 hv = hrow[k4];
        float hv_[4] = {hv.x, hv.y, hv.z, hv.w};
#pragma unroll
        for (int j = 0; j < 4; ++j) {
            float hk = hv_[j];
            int k = k4 * 4 + j;
#pragma unroll
            for (int c4 = 0; c4 < 16; ++c4) {
                float4 w = sWo1_4[k * 16 + c4];
                o1[c4 * 4]     = fmaf(hk, w.x, o1[c4 * 4]);
                o1[c4 * 4 + 1] = fmaf(hk, w.y, o1[c4 * 4 + 1]);
                o1[c4 * 4 + 2] = fmaf(hk, w.z, o1[c4 * 4 + 2]);
                o1[c4 * 4 + 3] = fmaf(hk, w.w, o1[c4 * 4 + 3]);
            }
        }
    }
    const float4* sWs2T_4 = (const float4*)sWs2T;
    for (int k = 0; k < 64; ++k) {
        float sek = sbs2[k];
#pragma unroll
        for (int j4 = 0; j4 < 8; ++j4) {
            float4 w = sWs2T_4[k * 8 + j4];
            sek = fmaf(hid[j4 * 4], w.x, fmaf(hid[j4 * 4 + 1], w.y,
                  fmaf(hid[j4 * 4 + 2], w.z, fmaf(hid[j4 * 4 + 3], w.w, sek))));
        }
#pragma unroll
        for (int c4 = 0; c4 < 16; ++c4) {
            float4 w = sWo1_4[(64 + k) * 16 + c4];
            o1[c4 * 4]     = fmaf(sek, w.x, o1[c4 * 4]);
            o1[c4 * 4 + 1] = fmaf(sek, w.y, o1[c4 * 4 + 1]);
            o1[c4 * 4 + 2] = fmaf(sek, w.z, o1[c4 * 4 + 2]);
            o1[c4 * 4 + 3] = fmaf(sek, w.w, o1[c4 * 4 + 3]);
        }
    }

    float o2[32];
    const float4* sbo2_4 = (const float4*)sbo2;
#pragma unroll
    for (int c4 = 0; c4 < 8; ++c4) {
        float4 v = sbo2_4[c4];
        o2[c4 * 4] = v.x; o2[c4 * 4 + 1] = v.y; o2[c4 * 4 + 2] = v.z; o2[c4 * 4 + 3] = v.w;
    }
    const float4* sWo2_4 = (const float4*)sWo2;
#pragma unroll
    for (int c = 0; c < 64; ++c) {
        float v = fmaxf(o1[c], 0.0f);
#pragma unroll
        for (int c4 = 0; c4 < 8; ++c4) {
            float4 w = sWo2_4[c * 8 + c4];
            o2[c4 * 4]     = fmaf(v, w.x, o2[c4 * 4]);
            o2[c4 * 4 + 1] = fmaf(v, w.y, o2[c4 * 4 + 1]);
            o2[c4 * 4 + 2] = fmaf(v, w.z, o2[c4 * 4 + 2]);
            o2[c4 * 4 + 3] = fmaf(v, w.w, o2[c4 * 4 + 3]);
        }
    }

    float o3 = bo3[0];
#pragma unroll
    for (int c2 = 0; c2 < 32; ++c2)
        o3 = fmaf(fmaxf(o2[c2], 0.0f), sWo3[c2], o3);

    out[i] = 1.0f / (1.0f + __expf(-o3));
}

// ==========================================================================
extern "C" void kernel_launch(void* const* d_in, const int* in_sizes, int n_in,
                              void* d_out, int out_size, void* d_ws, size_t ws_size,
                              hipStream_t stream) {
    const float* x     = (const float*)d_in[0];
    const int*   ei    = (const int*)d_in[1];
    const float* W_in  = (const float*)d_in[2];
    const float* b_in  = (const float*)d_in[3];
    const float* W_gcn = (const float*)d_in[4];
    const float* b_gcn = (const float*)d_in[5];
    const float* gamma = (const float*)d_in[6];
    const float* beta  = (const float*)d_in[7];
    const float* Ws1   = (const float*)d_in[8];
    const float* bs1   = (const float*)d_in[9];
    const float* Ws2   = (const float*)d_in[10];
    const float* bs2   = (const float*)d_in[11];
    const float* Wo1   = (const float*)d_in[12];
    const float* bo1   = (const float*)d_in[13];
    const float* Wo2   = (const float*)d_in[14];
    const float* bo2   = (const float*)d_in[15];
    const float* Wo3   = (const float*)d_in[16];
    const float* bo3   = (const float*)d_in[17];
    float* out = (float*)d_out;

    int n = in_sizes[0] / 128;
    int E = in_sizes[1] / 2;
    const int* row = ei;
    const int* col = ei + E;

    int npass8  = (n + NBU8 - 1) / NBU8;     // 2 @ n=100K
    int npass16 = (n + NB16 - 1) / NB16;     // 4 @ n=100K
    size_t NPU8  = (size_t)npass8 * NBU8;    // 131072
    size_t NPU16 = (size_t)npass16 * NB16;   // 131072

    auto al = [](size_t v) { return (v + 255) & ~(size_t)255; };
    size_t fixed = al((NPU8 + 256) * 4)          // roff
                 + al(NPU8 * 4)                  // cnt
                 + al(1024 * 4)                  // bsum
                 + 3 * al(NPU8 * 4)              // dis, odeg, infl
                 + al(NPU8 * 4)                  // odeg_i
                 + al(256)                       // maxima
                 + al((size_t)E * 4)             // esrc
                 + al((size_t)n * 64 * 4)        // h (f32)
                 + al((size_t)n * 64 * 2);       // hws (f16)
    int NB = 128;
    auto partBytes = [&](int nb) {
        size_t a = (size_t)nb * NPU8, b2 = (size_t)nb * NPU16 * 2;
        return a > b2 ? a : b2;
    };
    while (NB > 32 && fixed + partBytes(NB) > ws_size) NB >>= 1;
    int chunk = (E + NB - 1) / NB;

    char* p = (char*)d_ws;
    unsigned char*  part8  = (unsigned char*)p;     // [NB][NPU8] u8
    unsigned short* part16 = (unsigned short*)p;    // [NB][NPU16] u16 (later phase)
    p += al(partBytes(NB));
    int* roff = (int*)p;        p += al((NPU8 + 256) * 4);
    int* cnt  = (int*)p;        p += al(NPU8 * 4);
    int* bsum = (int*)p;        p += al(1024 * 4);
    float* dis  = (float*)p;    p += al(NPU8 * 4);
    float* odeg = (float*)p;    p += al(NPU8 * 4);
    float* infl = (float*)p;    p += al(NPU8 * 4);
    int* odeg_i = (int*)p;      p += al(NPU8 * 4);
    unsigned* maxima = (unsigned*)p; p += al(256);
    int* esrc = (int*)p;        p += al((size_t)E * 4);
    float* h   = (float*)p;     p += al((size_t)n * 64 * 4);
    unsigned* hws = (unsigned*)p;                   // half2-packed [n][32]

    int gn = (n + 255) / 256;                // <=512 for scan2

    k_init<<<1, 64, 0, stream>>>(maxima);

    // ---- col-CSR build (no global atomics) ----
    kh_hist<<<dim3(NB, npass8), TPBH, 0, stream>>>(col, part8, E, chunk, (int)NPU8);
    k_scan1<<<gn, 256, 0, stream>>>(part8, NB, (int)NPU8, cnt, roff, bsum, n);
    k_scan2<<<1, 512, 0, stream>>>(bsum, gn);
    k_scan3<<<gn, 256, 0, stream>>>(roff, bsum, cnt, dis, n, E);
    kh_prefix<<<gn, 256, 0, stream>>>(part8, NB, (int)NPU8, n);
    kh_fill<<<dim3(NB, npass8), TPBH, 0, stream>>>(col, row, roff, part8, esrc, E, chunk, (int)NPU8);

    // ---- structural stats ----
    kh_hist<<<dim3(NB, npass8), TPBH, 0, stream>>>(row, part8, E, chunk, (int)NPU8);
    kh_reduce_odeg<<<gn, 256, 0, stream>>>(part8, odeg, odeg_i, maxima, NB, (int)NPU8, n);
    kh_histacc<<<dim3(NB, npass16), TPBH, 0, stream>>>(row, col, odeg_i, part16, E, chunk, (int)NPU16);
    kh_reduce_infl<<<gn, 256, 0, stream>>>(part16, odeg, infl, maxima, NB, (int)NPU16, n);

    // ---- GNN ----
    k_in_proj<<<(n + 63) / 64, 256, 0, stream>>>(x, W_in, b_in, h, n);

    for (int l = 0; l < 3; ++l) {
        k_gcn_mm<<<(n + 63) / 64, 256, 0, stream>>>(h, W_gcn + (size_t)l * 64 * 64, dis, hws, n);
        k_gather<<<(n + 15) / 16, 256, 0, stream>>>(roff, esrc, (const uint2*)hws, dis,
                                                    b_gcn + l * 64, gamma + l * 64, beta + l * 64,
                                                    h, n);
    }

    k_final<<<gn, 256, 0, stream>>>(h, odeg, infl, maxima,
                                    Ws1, bs1, Ws2, bs2, Wo1, bo1, Wo2, bo2, Wo3, bo3,
                                    out, n);
}